// Round 1
// baseline (738.656 us; speedup 1.0000x reference)
//
#include <hip/hip_runtime.h>
#include <math.h>

#define NN 256
#define NE 4096
#define NC 128

// ---------------- fused conv3x3(SAME) + bias + relu + maxpool2x2 ----------------
// one thread = one pooled output pixel for one output channel (4 conv accumulators)
template<int CIN, int COUT, int HP, int CT>
__global__ __launch_bounds__(256) void conv_block_kernel(
    const float* __restrict__ in, const float* __restrict__ W,
    const float* __restrict__ bias, float* __restrict__ out)
{
    constexpr int H = HP * 2;
    const int tid = threadIdx.x;
    const int pix = tid & 63;        // 8x8 pooled pixels
    const int ocg = tid >> 6;        // 4 output channels per block
    const int lpy = pix >> 3, lpx = pix & 7;
    const int Y0 = blockIdx.y * 8, X0 = blockIdx.x * 8;
    const int oc = blockIdx.z * 4 + ocg;
    const int tY0 = 2 * Y0 - 1, tX0 = 2 * X0 - 1;
    __shared__ float tile[CT][18][20];
    float acc0 = 0.f, acc1 = 0.f, acc2 = 0.f, acc3 = 0.f;
    for (int c0 = 0; c0 < CIN; c0 += CT) {
        __syncthreads();
        for (int i = tid; i < CT * 324; i += 256) {
            int c = i / 324; int rem = i - c * 324;
            int r = rem / 18, col = rem - r * 18;
            int y = tY0 + r, x = tX0 + col;
            float v = 0.f;
            if (y >= 0 && y < H && x >= 0 && x < H)
                v = in[(size_t)(c0 + c) * (H * H) + y * H + x];
            tile[c][r][col] = v;
        }
        __syncthreads();
        #pragma unroll
        for (int c = 0; c < CT; ++c) {
            const float* wp = W + ((size_t)oc * CIN + (c0 + c)) * 9;
            float wreg[9];
            #pragma unroll
            for (int k = 0; k < 9; ++k) wreg[k] = wp[k];
            float p[4][4];
            #pragma unroll
            for (int r = 0; r < 4; ++r) {
                float2 a  = *(const float2*)&tile[c][2 * lpy + r][2 * lpx];
                float2 b2 = *(const float2*)&tile[c][2 * lpy + r][2 * lpx + 2];
                p[r][0] = a.x; p[r][1] = a.y; p[r][2] = b2.x; p[r][3] = b2.y;
            }
            #pragma unroll
            for (int ky = 0; ky < 3; ++ky) {
                #pragma unroll
                for (int kx = 0; kx < 3; ++kx) {
                    float w = wreg[ky * 3 + kx];
                    acc0 = fmaf(p[ky][kx],         w, acc0);
                    acc1 = fmaf(p[ky][kx + 1],     w, acc1);
                    acc2 = fmaf(p[ky + 1][kx],     w, acc2);
                    acc3 = fmaf(p[ky + 1][kx + 1], w, acc3);
                }
            }
        }
    }
    float m = fmaxf(fmaxf(acc0, acc1), fmaxf(acc2, acc3)) + bias[oc];
    m = fmaxf(m, 0.f);
    out[(size_t)oc * (HP * HP) + (Y0 + lpy) * HP + (X0 + lpx)] = m;
}

// ---------------- graph tail ----------------

// mean aggregation over edges: agg[n][f] = mean_{e: dst[e]==n} org[src[e]][f]
__global__ void sage_agg_kernel(const float* __restrict__ org,
                                const int* __restrict__ src, const int* __restrict__ dst,
                                float* __restrict__ agg)
{
    int node = blockIdx.x, f = threadIdx.x;
    float sum = 0.f; int cnt = 0;
    for (int e = 0; e < NE; ++e) {
        if (dst[e] == node) { cnt++; sum += org[src[e] * NN + f]; }
    }
    agg[node * NN + f] = (cnt > 0) ? sum / (float)cnt : 0.f;
}

__global__ void adj_zero_kernel(float* adj) { adj[blockIdx.x * 256 + threadIdx.x] = 0.f; }

__global__ void adj_build_kernel(const int* __restrict__ src, const int* __restrict__ dst,
                                 float* adj)
{
    int e = blockIdx.x * 256 + threadIdx.x;
    atomicAdd(&adj[src[e] * NN + dst[e]], 1.0f);  // sums of 1.0 are order-exact
}

// x1 = agg @ s1_wl + b + org @ s1_wr  -> (256,2)
__global__ void sage1_lin_kernel(const float* __restrict__ agg, const float* __restrict__ org,
                                 const float* __restrict__ wl, const float* __restrict__ wr,
                                 const float* __restrict__ b, float* __restrict__ x1)
{
    int t = blockIdx.x * 256 + threadIdx.x;   // 512 threads
    int n = t >> 1, p = t & 1;
    float acc = b[p];
    for (int k = 0; k < NN; ++k)
        acc += agg[n * NN + k] * wl[k * 2 + p] + org[n * NN + k] * wr[k * 2 + p];
    x1[n * 2 + p] = acc;
}

// s_pre = agg @ s2_wl + b + org @ s2_wr -> (256,128)
__global__ void sage2_lin_kernel(const float* __restrict__ agg, const float* __restrict__ org,
                                 const float* __restrict__ wl, const float* __restrict__ wr,
                                 const float* __restrict__ b, float* __restrict__ s_pre)
{
    int n = blockIdx.x, p = threadIdx.x;
    float acc = b[p];
    for (int k = 0; k < NN; ++k)
        acc += agg[n * NN + k] * wl[k * NC + p] + org[n * NN + k] * wr[k * NC + p];
    s_pre[n * NC + p] = acc;
}

__global__ void softmax_kernel(const float* __restrict__ s_pre, float* __restrict__ s_soft)
{
    int n = blockIdx.x, p = threadIdx.x;  // 128 threads
    __shared__ float red[128];
    float v = s_pre[n * NC + p];
    red[p] = v; __syncthreads();
    for (int s = 64; s > 0; s >>= 1) { if (p < s) red[p] = fmaxf(red[p], red[p + s]); __syncthreads(); }
    float m = red[0]; __syncthreads();
    float e = expf(v - m);
    red[p] = e; __syncthreads();
    for (int s = 64; s > 0; s >>= 1) { if (p < s) red[p] += red[p + s]; __syncthreads(); }
    s_soft[n * NC + p] = e / red[0];
}

__global__ void ent_kernel(const float* __restrict__ s_soft, float* __restrict__ out)
{
    int t = threadIdx.x;
    float a = 0.f;
    for (int i = t; i < NN * NC; i += 256) { float p = s_soft[i]; a -= p * logf(p + 1e-15f); }
    __shared__ float red[256];
    red[t] = a; __syncthreads();
    for (int s = 128; s > 0; s >>= 1) { if (t < s) red[t] += red[t + s]; __syncthreads(); }
    if (t == 0) out[0] = red[0] / (float)NN;
}

// per-row partial sums of ||adj - s s^T||^2
__global__ void linkpart_kernel(const float* __restrict__ adj, const float* __restrict__ s_soft,
                                float* __restrict__ partial)
{
    int i = blockIdx.x, j = threadIdx.x;  // 256 threads
    __shared__ float si[NC];
    if (j < NC) si[j] = s_soft[i * NC + j];
    __syncthreads();
    float dot = 0.f;
    for (int k = 0; k < NC; ++k) dot += si[k] * s_soft[j * NC + k];
    float d = adj[i * NN + j] - dot;
    float v = d * d;
    __shared__ float red[256];
    red[j] = v; __syncthreads();
    for (int s = 128; s > 0; s >>= 1) { if (j < s) red[j] += red[j + s]; __syncthreads(); }
    if (j == 0) partial[i] = red[0];
}

__global__ void linkfinal_kernel(const float* __restrict__ partial, float* __restrict__ out)
{
    int t = threadIdx.x;
    __shared__ float red[256];
    red[t] = partial[t]; __syncthreads();
    for (int s = 128; s > 0; s >>= 1) { if (t < s) red[t] += red[t + s]; __syncthreads(); }
    if (t == 0) out[0] = sqrtf(red[0]) / (float)(NN * NN);
}

// x_pool = s_soft^T @ x1 ; nodes = tanh(x_pool) -> (128,2), write ws + d_out
__global__ void xpool_kernel(const float* __restrict__ s_soft, const float* __restrict__ x1,
                             float* __restrict__ nodes_ws, float* __restrict__ nodes_out)
{
    int t = threadIdx.x;  // 256
    int c = t >> 1, p = t & 1;
    float acc = 0.f;
    for (int n = 0; n < NN; ++n) acc += s_soft[n * NC + c] * x1[n * 2 + p];
    float nd = tanhf(acc);
    nodes_ws[c * 2 + p] = nd;
    nodes_out[c * 2 + p] = nd;
}

// T = adj @ s_soft  (256,128)
__global__ void adjT_kernel(const float* __restrict__ adj, const float* __restrict__ s_soft,
                            float* __restrict__ T)
{
    int n = blockIdx.x, p = threadIdx.x;
    float acc = 0.f;
    for (int k = 0; k < NN; ++k) acc += adj[n * NN + k] * s_soft[k * NC + p];
    T[n * NC + p] = acc;
}

// adj_pool = s_soft^T @ T  (128,128)
__global__ void adjpool_kernel(const float* __restrict__ s_soft, const float* __restrict__ T,
                               float* __restrict__ adj_pool)
{
    int c = blockIdx.x, p = threadIdx.x;
    float acc = 0.f;
    for (int n = 0; n < NN; ++n) acc += s_soft[n * NC + c] * T[n * NC + p];
    adj_pool[c * NC + p] = acc;
}

__global__ void edgebin_kernel(const float* __restrict__ adj_pool, float* __restrict__ eb)
{
    int c = blockIdx.x, p = threadIdx.x;  // 128 threads
    __shared__ float red[128];
    float v = adj_pool[c * NC + p];
    red[p] = v; __syncthreads();
    for (int s = 64; s > 0; s >>= 1) { if (p < s) red[p] = fmaxf(red[p], red[p + s]); __syncthreads(); }
    eb[c * NC + p] = (v == red[0]) ? 1.f : 0.f;
}

// out = agg3 @ s3_wl + b + nodes @ s3_wr   (128,2)
__global__ void sage3_kernel(const float* __restrict__ eb, const float* __restrict__ nodes,
                             const float* __restrict__ wl, const float* __restrict__ wr,
                             const float* __restrict__ b, float* __restrict__ out)
{
    int j = threadIdx.x;  // 128
    float indeg = 0.f, a0 = 0.f, a1 = 0.f;
    for (int i = 0; i < NC; ++i) {
        float e = eb[i * NC + j];
        indeg += e;
        a0 += e * nodes[i * 2 + 0];
        a1 += e * nodes[i * 2 + 1];
    }
    float inv = (indeg > 0.f) ? 1.f / fmaxf(indeg, 1.f) : 0.f;
    float g0 = a0 * inv, g1 = a1 * inv;
    float n0 = nodes[j * 2 + 0], n1 = nodes[j * 2 + 1];
    out[j * 2 + 0] = g0 * wl[0] + g1 * wl[2] + b[0] + n0 * wr[0] + n1 * wr[2];
    out[j * 2 + 1] = g0 * wl[1] + g1 * wl[3] + b[1] + n0 * wr[1] + n1 * wr[3];
}

extern "C" void kernel_launch(void* const* d_in, const int* in_sizes, int n_in,
                              void* d_out, int out_size, void* d_ws, size_t ws_size,
                              hipStream_t stream)
{
    const float* input = (const float*)d_in[0];
    const int* eidx = (const int*)d_in[1];
    const int* src = eidx;
    const int* dst = eidx + NE;
    const float* w1 = (const float*)d_in[2];  const float* b1 = (const float*)d_in[3];
    const float* w2 = (const float*)d_in[4];  const float* b2 = (const float*)d_in[5];
    const float* w3 = (const float*)d_in[6];  const float* b3 = (const float*)d_in[7];
    const float* w4 = (const float*)d_in[8];  const float* b4 = (const float*)d_in[9];
    const float* w5 = (const float*)d_in[10]; const float* b5 = (const float*)d_in[11];
    const float* s1_wl = (const float*)d_in[12]; const float* s1_wr = (const float*)d_in[13];
    const float* s1_b  = (const float*)d_in[14];
    const float* s2_wl = (const float*)d_in[15]; const float* s2_wr = (const float*)d_in[16];
    const float* s2_b  = (const float*)d_in[17];
    const float* s3_wl = (const float*)d_in[18]; const float* s3_wr = (const float*)d_in[19];
    const float* s3_b  = (const float*)d_in[20];

    float* ws = (float*)d_ws;
    float* A       = ws;                    // 32*256*256 = 2097152
    float* B       = A + 2097152;           // 64*128*128 = 1048576
    float* org     = B + 1048576;           // 256*256
    float* agg     = org + 65536;           // 256*256
    float* adj     = agg + 65536;           // 256*256
    float* s_pre   = adj + 65536;           // 256*128
    float* s_soft  = s_pre + 32768;         // 256*128
    float* T       = s_soft + 32768;        // 256*128
    float* adjp    = T + 32768;             // 128*128
    float* x1g     = adjp + 16384;          // 256*2
    float* nodesb  = x1g + 512;             // 128*2
    float* partial = nodesb + 256;          // 256

    float* fout = (float*)d_out;
    float* out_main  = fout;         // 256
    float* out_link  = fout + 256;   // 1
    float* out_ent   = fout + 257;   // 1
    float* out_nodes = fout + 258;   // 256
    float* out_eb    = fout + 514;   // 16384

    // conv trunk (ping-pong A/B)
    conv_block_kernel<3,   32, 256, 3><<<dim3(32, 32, 8),  256, 0, stream>>>(input, w1, b1, A);
    conv_block_kernel<32,  64, 128, 4><<<dim3(16, 16, 16), 256, 0, stream>>>(A, w2, b2, B);
    conv_block_kernel<64, 128,  64, 4><<<dim3(8, 8, 32),   256, 0, stream>>>(B, w3, b3, A);
    conv_block_kernel<128,256,  32, 4><<<dim3(4, 4, 64),   256, 0, stream>>>(A, w4, b4, B);
    conv_block_kernel<256,256,  16, 4><<<dim3(2, 2, 64),   256, 0, stream>>>(B, w5, b5, org);

    // graph tail
    sage_agg_kernel<<<256, 256, 0, stream>>>(org, src, dst, agg);
    adj_zero_kernel<<<256, 256, 0, stream>>>(adj);
    adj_build_kernel<<<16, 256, 0, stream>>>(src, dst, adj);
    sage1_lin_kernel<<<2, 256, 0, stream>>>(agg, org, s1_wl, s1_wr, s1_b, x1g);
    sage2_lin_kernel<<<256, 128, 0, stream>>>(agg, org, s2_wl, s2_wr, s2_b, s_pre);
    softmax_kernel<<<256, 128, 0, stream>>>(s_pre, s_soft);
    ent_kernel<<<1, 256, 0, stream>>>(s_soft, out_ent);
    linkpart_kernel<<<256, 256, 0, stream>>>(adj, s_soft, partial);
    linkfinal_kernel<<<1, 256, 0, stream>>>(partial, out_link);
    xpool_kernel<<<1, 256, 0, stream>>>(s_soft, x1g, nodesb, out_nodes);
    adjT_kernel<<<256, 128, 0, stream>>>(adj, s_soft, T);
    adjpool_kernel<<<128, 128, 0, stream>>>(s_soft, T, adjp);
    edgebin_kernel<<<128, 128, 0, stream>>>(adjp, out_eb);
    sage3_kernel<<<1, 128, 0, stream>>>(out_eb, nodesb, s3_wl, s3_wr, s3_b, out_main);
}

// Round 2
// 389.659 us; speedup vs baseline: 1.8956x; 1.8956x over previous
//
#include <hip/hip_runtime.h>
#include <math.h>

#define NN 256
#define NE 4096
#define NC 128

// ============ fused conv3x3(SAME)+bias+relu+maxpool2x2 (or partial pre-pool) ============
// 256 threads = 32 pixel-pairs (8x8 pooled tile, 2 horizontally adjacent pooled px per
// thread) x 8 oc-groups. Each thread computes OCPT out-channels x 8 conv pixels.
// CSPLIT>1: write pre-pool partial sums (no bias/relu/pool) to out[cs][COUT][H][H].
template<int CIN, int COUT, int HP, int CT, int OCPT, int CSPLIT>
__global__ __launch_bounds__(256) void conv_block(
    const float* __restrict__ in, const float* __restrict__ Wt,
    const float* __restrict__ bias, float* __restrict__ out)
{
    constexpr int H = HP * 2;
    constexpr int CCH = CIN / CSPLIT;
    constexpr int OCB = 8 * OCPT;
    const int tid = threadIdx.x;
    const int pp  = tid & 31;
    const int ocg = tid >> 5;
    const int lpy = pp >> 2;
    const int ppx = pp & 3;
    const int X0 = blockIdx.x * 8, Y0 = blockIdx.y * 8;
    const int bz = blockIdx.z;
    const int cs = bz % CSPLIT;
    const int og = bz / CSPLIT;
    const int ocbase = og * OCB;
    const int tY0 = 2 * Y0 - 1, tX0 = 2 * X0 - 1;

    __shared__ float tile[CT][18][20];
    __shared__ float wlds[OCB][CCH][12];

    // stage this block's weights once (OCB ocs x CCH channels x 9 taps)
    for (int i = tid; i < OCB * CCH * 9; i += 256) {
        int o = i / (CCH * 9); int r = i - o * (CCH * 9);
        int c = r / 9; int k = r - c * 9;
        wlds[o][c][k] = Wt[((size_t)(ocbase + o) * CIN + cs * CCH + c) * 9 + k];
    }

    float acc[OCPT][2][2][2];
    #pragma unroll
    for (int o = 0; o < OCPT; ++o)
        #pragma unroll
        for (int q = 0; q < 2; ++q)
            #pragma unroll
            for (int py = 0; py < 2; ++py)
                #pragma unroll
                for (int qx = 0; qx < 2; ++qx) acc[o][q][py][qx] = 0.f;

    for (int c0 = 0; c0 < CCH; c0 += CT) {
        __syncthreads();  // also makes wlds visible on first iteration
        for (int i = tid; i < CT * 324; i += 256) {
            int c = i / 324; int rem = i - c * 324;
            int r = rem / 18, col = rem - r * 18;
            int y = tY0 + r, x = tX0 + col;
            float v = 0.f;
            if (y >= 0 && y < H && x >= 0 && x < H)
                v = in[(size_t)(cs * CCH + c0 + c) * (H * H) + y * H + x];
            tile[c][r][col] = v;
        }
        __syncthreads();
        #pragma unroll
        for (int c = 0; c < CT; ++c) {
            float p[4][6];
            #pragma unroll
            for (int r = 0; r < 4; ++r) {
                float2 a = *(const float2*)&tile[c][2 * lpy + r][4 * ppx];
                float2 b = *(const float2*)&tile[c][2 * lpy + r][4 * ppx + 2];
                float2 d = *(const float2*)&tile[c][2 * lpy + r][4 * ppx + 4];
                p[r][0] = a.x; p[r][1] = a.y; p[r][2] = b.x;
                p[r][3] = b.y; p[r][4] = d.x; p[r][5] = d.y;
            }
            #pragma unroll
            for (int o = 0; o < OCPT; ++o) {
                const float* wp = &wlds[ocg * OCPT + o][c0 + c][0];
                float4 w0 = *(const float4*)(wp);
                float4 w1 = *(const float4*)(wp + 4);
                float w8 = wp[8];
                float wk[9] = {w0.x, w0.y, w0.z, w0.w, w1.x, w1.y, w1.z, w1.w, w8};
                #pragma unroll
                for (int ky = 0; ky < 3; ++ky)
                    #pragma unroll
                    for (int kx = 0; kx < 3; ++kx) {
                        float w = wk[ky * 3 + kx];
                        #pragma unroll
                        for (int py = 0; py < 2; ++py)
                            #pragma unroll
                            for (int q = 0; q < 2; ++q)
                                #pragma unroll
                                for (int qx = 0; qx < 2; ++qx)
                                    acc[o][q][py][qx] =
                                        fmaf(p[py + ky][2 * q + qx + kx], w, acc[o][q][py][qx]);
                    }
            }
        }
    }

    if constexpr (CSPLIT == 1) {
        #pragma unroll
        for (int o = 0; o < OCPT; ++o) {
            int oc = ocbase + ocg * OCPT + o;
            float b = bias[oc];
            float2 r;
            r.x = fmaxf(fmaxf(fmaxf(acc[o][0][0][0], acc[o][0][0][1]),
                              fmaxf(acc[o][0][1][0], acc[o][0][1][1])) + b, 0.f);
            r.y = fmaxf(fmaxf(fmaxf(acc[o][1][0][0], acc[o][1][0][1]),
                              fmaxf(acc[o][1][1][0], acc[o][1][1][1])) + b, 0.f);
            *(float2*)&out[(size_t)oc * HP * HP + (Y0 + lpy) * HP + X0 + 2 * ppx] = r;
        }
    } else {
        #pragma unroll
        for (int o = 0; o < OCPT; ++o) {
            int oc = ocbase + ocg * OCPT + o;
            size_t base = ((size_t)(cs * COUT + oc) * H + 2 * (Y0 + lpy)) * H + 2 * X0 + 4 * ppx;
            float4 v0 = {acc[o][0][0][0], acc[o][0][0][1], acc[o][1][0][0], acc[o][1][0][1]};
            float4 v1 = {acc[o][0][1][0], acc[o][0][1][1], acc[o][1][1][0], acc[o][1][1][1]};
            *(float4*)&out[base]     = v0;
            *(float4*)&out[base + H] = v1;
        }
    }
}

// sum CSPLIT pre-pool partials, add bias, relu, 2x2 maxpool
template<int COUT, int HP, int CS>
__global__ void finalize_pool(const float* __restrict__ partial, const float* __restrict__ bias,
                              float* __restrict__ out)
{
    int idx = blockIdx.x * 256 + threadIdx.x;
    if (idx >= COUT * HP * HP) return;
    constexpr int H = HP * 2;
    int x = idx & (HP - 1); int rest = idx / HP;
    int y = rest & (HP - 1); int oc = rest / HP;
    float v00 = 0.f, v01 = 0.f, v10 = 0.f, v11 = 0.f;
    #pragma unroll
    for (int cs = 0; cs < CS; ++cs) {
        const float* p = partial + ((size_t)(cs * COUT + oc) * H + 2 * y) * H + 2 * x;
        v00 += p[0]; v01 += p[1]; v10 += p[H]; v11 += p[H + 1];
    }
    float m = fmaxf(fmaxf(v00, v01), fmaxf(v10, v11)) + bias[oc];
    out[idx] = fmaxf(m, 0.f);
}

// ============ graph tail ============

__global__ void zero_kernel(float* p) { p[blockIdx.x * 256 + threadIdx.x] = 0.f; }

__global__ void adj_build_kernel(const int* __restrict__ src, const int* __restrict__ dst,
                                 float* adj, float* adjT)
{
    int e = blockIdx.x * 256 + threadIdx.x;
    int s = src[e], d = dst[e];
    atomicAdd(&adj[s * NN + d], 1.0f);   // sums of 1.0 are order-exact
    atomicAdd(&adjT[d * NN + s], 1.0f);
}

// mean agg via adjT: agg[n][f] = (sum_s adjT[n][s]*org[s][f]) / cnt[n]
__global__ void agg_kernel(const float* __restrict__ adjT, const float* __restrict__ org,
                           float* __restrict__ agg)
{
    int n = blockIdx.x, f = threadIdx.x;  // 256 threads
    __shared__ float row[NN];
    __shared__ float red[256];
    float r = adjT[n * NN + f];
    row[f] = r; red[f] = r;
    __syncthreads();
    for (int s = 128; s > 0; s >>= 1) { if (f < s) red[f] += red[f + s]; __syncthreads(); }
    float cnt = red[0];
    float acc = 0.f;
    #pragma unroll 4
    for (int s = 0; s < NN; ++s) acc = fmaf(row[s], org[s * NN + f], acc);
    agg[n * NN + f] = (cnt > 0.f) ? acc / cnt : 0.f;
}

// x1 = agg @ s1_wl + b + org @ s1_wr  -> (256,2)
__global__ void sage1_lin_kernel(const float* __restrict__ agg, const float* __restrict__ org,
                                 const float* __restrict__ wl, const float* __restrict__ wr,
                                 const float* __restrict__ b, float* __restrict__ x1)
{
    int t = blockIdx.x * 256 + threadIdx.x;
    int n = t >> 1, p = t & 1;
    float acc = b[p];
    for (int k = 0; k < NN; ++k)
        acc += agg[n * NN + k] * wl[k * 2 + p] + org[n * NN + k] * wr[k * 2 + p];
    x1[n * 2 + p] = acc;
}

// s_pre = agg @ s2_wl + b + org @ s2_wr -> (256,128)
__global__ void sage2_lin_kernel(const float* __restrict__ agg, const float* __restrict__ org,
                                 const float* __restrict__ wl, const float* __restrict__ wr,
                                 const float* __restrict__ b, float* __restrict__ s_pre)
{
    int n = blockIdx.x, p = threadIdx.x;
    float acc = b[p];
    for (int k = 0; k < NN; ++k)
        acc += agg[n * NN + k] * wl[k * NC + p] + org[n * NN + k] * wr[k * NC + p];
    s_pre[n * NC + p] = acc;
}

__global__ void softmax_kernel(const float* __restrict__ s_pre, float* __restrict__ s_soft)
{
    int n = blockIdx.x, p = threadIdx.x;  // 128 threads
    __shared__ float red[128];
    float v = s_pre[n * NC + p];
    red[p] = v; __syncthreads();
    for (int s = 64; s > 0; s >>= 1) { if (p < s) red[p] = fmaxf(red[p], red[p + s]); __syncthreads(); }
    float m = red[0]; __syncthreads();
    float e = expf(v - m);
    red[p] = e; __syncthreads();
    for (int s = 64; s > 0; s >>= 1) { if (p < s) red[p] += red[p + s]; __syncthreads(); }
    s_soft[n * NC + p] = e / red[0];
}

__global__ void ent_kernel(const float* __restrict__ s_soft, float* __restrict__ out)
{
    int t = threadIdx.x;
    float a = 0.f;
    for (int i = t; i < NN * NC; i += 256) { float p = s_soft[i]; a -= p * logf(p + 1e-15f); }
    __shared__ float red[256];
    red[t] = a; __syncthreads();
    for (int s = 128; s > 0; s >>= 1) { if (t < s) red[t] += red[t + s]; __syncthreads(); }
    if (t == 0) out[0] = red[0] / (float)NN;
}

__global__ void linkpart_kernel(const float* __restrict__ adj, const float* __restrict__ s_soft,
                                float* __restrict__ partial)
{
    int i = blockIdx.x, j = threadIdx.x;  // 256 threads
    __shared__ float si[NC];
    if (j < NC) si[j] = s_soft[i * NC + j];
    __syncthreads();
    float dot = 0.f;
    for (int k = 0; k < NC; ++k) dot += si[k] * s_soft[j * NC + k];
    float d = adj[i * NN + j] - dot;
    float v = d * d;
    __shared__ float red[256];
    red[j] = v; __syncthreads();
    for (int s = 128; s > 0; s >>= 1) { if (j < s) red[j] += red[j + s]; __syncthreads(); }
    if (j == 0) partial[i] = red[0];
}

__global__ void linkfinal_kernel(const float* __restrict__ partial, float* __restrict__ out)
{
    int t = threadIdx.x;
    __shared__ float red[256];
    red[t] = partial[t]; __syncthreads();
    for (int s = 128; s > 0; s >>= 1) { if (t < s) red[t] += red[t + s]; __syncthreads(); }
    if (t == 0) out[0] = sqrtf(red[0]) / (float)(NN * NN);
}

__global__ void xpool_kernel(const float* __restrict__ s_soft, const float* __restrict__ x1,
                             float* __restrict__ nodes_ws, float* __restrict__ nodes_out)
{
    int t = threadIdx.x;  // 256
    int c = t >> 1, p = t & 1;
    float acc = 0.f;
    for (int n = 0; n < NN; ++n) acc += s_soft[n * NC + c] * x1[n * 2 + p];
    float nd = tanhf(acc);
    nodes_ws[c * 2 + p] = nd;
    nodes_out[c * 2 + p] = nd;
}

__global__ void adjT_mm_kernel(const float* __restrict__ adj, const float* __restrict__ s_soft,
                               float* __restrict__ T)
{
    int n = blockIdx.x, p = threadIdx.x;
    float acc = 0.f;
    for (int k = 0; k < NN; ++k) acc += adj[n * NN + k] * s_soft[k * NC + p];
    T[n * NC + p] = acc;
}

__global__ void adjpool_kernel(const float* __restrict__ s_soft, const float* __restrict__ T,
                               float* __restrict__ adj_pool)
{
    int c = blockIdx.x, p = threadIdx.x;
    float acc = 0.f;
    for (int n = 0; n < NN; ++n) acc += s_soft[n * NC + c] * T[n * NC + p];
    adj_pool[c * NC + p] = acc;
}

__global__ void edgebin_kernel(const float* __restrict__ adj_pool, float* __restrict__ eb)
{
    int c = blockIdx.x, p = threadIdx.x;  // 128 threads
    __shared__ float red[128];
    float v = adj_pool[c * NC + p];
    red[p] = v; __syncthreads();
    for (int s = 64; s > 0; s >>= 1) { if (p < s) red[p] = fmaxf(red[p], red[p + s]); __syncthreads(); }
    eb[c * NC + p] = (v == red[0]) ? 1.f : 0.f;
}

__global__ void sage3_kernel(const float* __restrict__ eb, const float* __restrict__ nodes,
                             const float* __restrict__ wl, const float* __restrict__ wr,
                             const float* __restrict__ b, float* __restrict__ out)
{
    int j = threadIdx.x;  // 128
    float indeg = 0.f, a0 = 0.f, a1 = 0.f;
    for (int i = 0; i < NC; ++i) {
        float e = eb[i * NC + j];
        indeg += e;
        a0 += e * nodes[i * 2 + 0];
        a1 += e * nodes[i * 2 + 1];
    }
    float inv = (indeg > 0.f) ? 1.f / fmaxf(indeg, 1.f) : 0.f;
    float g0 = a0 * inv, g1 = a1 * inv;
    float n0 = nodes[j * 2 + 0], n1 = nodes[j * 2 + 1];
    out[j * 2 + 0] = g0 * wl[0] + g1 * wl[2] + b[0] + n0 * wr[0] + n1 * wr[2];
    out[j * 2 + 1] = g0 * wl[1] + g1 * wl[3] + b[1] + n0 * wr[1] + n1 * wr[3];
}

extern "C" void kernel_launch(void* const* d_in, const int* in_sizes, int n_in,
                              void* d_out, int out_size, void* d_ws, size_t ws_size,
                              hipStream_t stream)
{
    const float* input = (const float*)d_in[0];
    const int* eidx = (const int*)d_in[1];
    const int* src = eidx;
    const int* dst = eidx + NE;
    const float* w1 = (const float*)d_in[2];  const float* b1 = (const float*)d_in[3];
    const float* w2 = (const float*)d_in[4];  const float* b2 = (const float*)d_in[5];
    const float* w3 = (const float*)d_in[6];  const float* b3 = (const float*)d_in[7];
    const float* w4 = (const float*)d_in[8];  const float* b4 = (const float*)d_in[9];
    const float* w5 = (const float*)d_in[10]; const float* b5 = (const float*)d_in[11];
    const float* s1_wl = (const float*)d_in[12]; const float* s1_wr = (const float*)d_in[13];
    const float* s1_b  = (const float*)d_in[14];
    const float* s2_wl = (const float*)d_in[15]; const float* s2_wr = (const float*)d_in[16];
    const float* s2_b  = (const float*)d_in[17];
    const float* s3_wl = (const float*)d_in[18]; const float* s3_wr = (const float*)d_in[19];
    const float* s3_b  = (const float*)d_in[20];

    float* ws = (float*)d_ws;
    // region plan (floats):
    //  X   [0,        2097152)  conv1 out; later conv3 out [0,524288); later conv5 partial
    //  Y   [2097152,  3145728)  conv2 out (dead after conv3)
    //  P4  [524288,   2621440)  conv4 partial (2x256x64x64), lives in dead X-tail + Y
    //  W4  [2621440,  2883584)  conv4 out (inside dead Y)
    //  ORG [2883584,  2949120)
    //  graph buffers reuse [0, ~320K) after conv5
    float* X   = ws;
    float* Y   = ws + 2097152;
    float* P4  = ws + 524288;
    float* W4  = ws + 2621440;
    float* ORG = ws + 2883584;

    float* adj    = ws;              // 65536
    float* adjT   = ws + 65536;      // 65536
    float* agg    = ws + 131072;     // 65536
    float* s_pre  = ws + 196608;     // 32768
    float* s_soft = ws + 229376;     // 32768
    float* T      = ws + 262144;     // 32768
    float* adjp   = ws + 294912;     // 16384
    float* x1g    = ws + 311296;     // 512
    float* nodesb = ws + 311808;     // 256
    float* lpart  = ws + 312064;     // 256

    float* fout = (float*)d_out;
    float* out_main  = fout;         // 256
    float* out_link  = fout + 256;   // 1
    float* out_ent   = fout + 257;   // 1
    float* out_nodes = fout + 258;   // 256
    float* out_eb    = fout + 514;   // 16384

    // conv trunk
    conv_block<3,   32, 256, 3, 2, 1><<<dim3(32, 32, 2),   256, 0, stream>>>(input, w1, b1, X);
    conv_block<32,  64, 128, 4, 2, 1><<<dim3(16, 16, 4),   256, 0, stream>>>(X, w2, b2, Y);
    conv_block<64, 128,  64, 4, 1, 1><<<dim3(8, 8, 16),    256, 0, stream>>>(Y, w3, b3, X);
    conv_block<128,256,  32, 4, 1, 2><<<dim3(4, 4, 64),    256, 0, stream>>>(X, w4, nullptr, P4);
    finalize_pool<256, 32, 2><<<1024, 256, 0, stream>>>(P4, b4, W4);
    conv_block<256,256,  16, 4, 1, 8><<<dim3(2, 2, 256),   256, 0, stream>>>(W4, w5, nullptr, X);
    finalize_pool<256, 16, 8><<<256, 256, 0, stream>>>(X, b5, ORG);

    // graph tail
    zero_kernel<<<512, 256, 0, stream>>>(adj);  // zeros adj + adjT (contiguous 131072)
    adj_build_kernel<<<16, 256, 0, stream>>>(src, dst, adj, adjT);
    agg_kernel<<<256, 256, 0, stream>>>(adjT, ORG, agg);
    sage1_lin_kernel<<<2, 256, 0, stream>>>(agg, ORG, s1_wl, s1_wr, s1_b, x1g);
    sage2_lin_kernel<<<256, 128, 0, stream>>>(agg, ORG, s2_wl, s2_wr, s2_b, s_pre);
    softmax_kernel<<<256, 128, 0, stream>>>(s_pre, s_soft);
    ent_kernel<<<1, 256, 0, stream>>>(s_soft, out_ent);
    linkpart_kernel<<<256, 256, 0, stream>>>(adj, s_soft, lpart);
    linkfinal_kernel<<<1, 256, 0, stream>>>(lpart, out_link);
    xpool_kernel<<<1, 256, 0, stream>>>(s_soft, x1g, nodesb, out_nodes);
    adjT_mm_kernel<<<256, 128, 0, stream>>>(adj, s_soft, T);
    adjpool_kernel<<<128, 128, 0, stream>>>(s_soft, T, adjp);
    edgebin_kernel<<<128, 128, 0, stream>>>(adjp, out_eb);
    sage3_kernel<<<1, 128, 0, stream>>>(out_eb, nodesb, s3_wl, s3_wr, s3_b, out_main);
}

// Round 4
// 206.136 us; speedup vs baseline: 3.5833x; 1.8903x over previous
//
#include <hip/hip_runtime.h>
#include <math.h>

#define NN 256
#define NE 4096
#define NC 128

using short8 = __attribute__((ext_vector_type(8))) short;
using f32x4  = __attribute__((ext_vector_type(4))) float;

static __device__ __forceinline__ unsigned short f2bf(float x) {
    unsigned u = __float_as_uint(x);
    unsigned r = (u + 0x7FFF + ((u >> 16) & 1)) >> 16;   // RNE
    return (unsigned short)r;
}

// ================= conv1: f32 VALU, CIN=3, COUT=32, 512^2 -> pooled 256^2 =================
// out: channels-last bf16 [256][256][32]
__global__ __launch_bounds__(256) void conv1_kernel(
    const float* __restrict__ in, const float* __restrict__ W,
    const float* __restrict__ bias, unsigned short* __restrict__ out)
{
    const int tid = threadIdx.x;
    const int pp = tid & 31, ocg = tid >> 5;     // 8 oc-groups x 4 oc
    const int lpy = pp >> 2, ppx = pp & 3;
    const int X0 = blockIdx.x * 8, Y0 = blockIdx.y * 8;
    const int tY0 = 2 * Y0 - 1, tX0 = 2 * X0 - 1;
    __shared__ float tile[3][18][20];
    __shared__ float wlds[32][3][12];
    for (int i = tid; i < 864; i += 256) {
        int o = i / 27, r = i - o * 27;
        int c = r / 9, k = r - c * 9;
        wlds[o][c][k] = W[i];
    }
    for (int i = tid; i < 3 * 324; i += 256) {
        int c = i / 324, rem = i - c * 324;
        int r = rem / 18, col = rem - r * 18;
        int y = tY0 + r, x = tX0 + col;
        float v = 0.f;
        if (y >= 0 && y < 512 && x >= 0 && x < 512) {
            v = in[c * 512 * 512 + y * 512 + x];
        }
        tile[c][r][col] = v;
    }
    __syncthreads();
    float acc[4][2][2][2] = {};
    #pragma unroll
    for (int c = 0; c < 3; ++c) {
        float p[4][6];
        #pragma unroll
        for (int r = 0; r < 4; ++r) {
            float2 a  = *(const float2*)&tile[c][2 * lpy + r][4 * ppx];
            float2 b2 = *(const float2*)&tile[c][2 * lpy + r][4 * ppx + 2];
            float2 d  = *(const float2*)&tile[c][2 * lpy + r][4 * ppx + 4];
            p[r][0] = a.x; p[r][1] = a.y; p[r][2] = b2.x;
            p[r][3] = b2.y; p[r][4] = d.x; p[r][5] = d.y;
        }
        #pragma unroll
        for (int o = 0; o < 4; ++o) {
            const float* wp = &wlds[ocg * 4 + o][c][0];
            float4 w0 = *(const float4*)(wp);
            float4 w1 = *(const float4*)(wp + 4);
            float w8 = wp[8];
            float wk[9] = {w0.x, w0.y, w0.z, w0.w, w1.x, w1.y, w1.z, w1.w, w8};
            #pragma unroll
            for (int ky = 0; ky < 3; ++ky) {
                #pragma unroll
                for (int kx = 0; kx < 3; ++kx) {
                    float w = wk[ky * 3 + kx];
                    #pragma unroll
                    for (int py = 0; py < 2; ++py) {
                        #pragma unroll
                        for (int q = 0; q < 2; ++q) {
                            #pragma unroll
                            for (int qx = 0; qx < 2; ++qx) {
                                acc[o][q][py][qx] =
                                    fmaf(p[py + ky][2 * q + qx + kx], w, acc[o][q][py][qx]);
                            }
                        }
                    }
                }
            }
        }
    }
    #pragma unroll
    for (int q = 0; q < 2; ++q) {
        unsigned u0 = 0, u1 = 0;
        #pragma unroll
        for (int o = 0; o < 4; ++o) {
            float b = bias[ocg * 4 + o];
            float m = fmaxf(fmaxf(acc[o][q][0][0], acc[o][q][0][1]),
                            fmaxf(acc[o][q][1][0], acc[o][q][1][1])) + b;
            m = fmaxf(m, 0.f);
            unsigned short hb = f2bf(m);
            if (o == 0) { u0 = hb; }
            else if (o == 1) { u0 |= (unsigned)hb << 16; }
            else if (o == 2) { u1 = hb; }
            else { u1 |= (unsigned)hb << 16; }
        }
        uint2 uu; uu.x = u0; uu.y = u1;
        *(uint2*)&out[((size_t)((Y0 + lpy) * 256 + X0 + 2 * ppx + q)) * 32 + ocg * 4] = uu;
    }
}

// ================= weight pre-fragmentation (all 4 MFMA convs in one kernel) =================
// layout: [t(9)][g(COUT/16)][c(CIN/32)][lane(64)][8]  bf16; A-frag: oc=lane&15, k=(lane>>4)*8+j
__global__ void wfrag_prep_all(const float* __restrict__ w2, const float* __restrict__ w3,
                               const float* __restrict__ w4, const float* __restrict__ w5,
                               unsigned short* __restrict__ f2, unsigned short* __restrict__ f3,
                               unsigned short* __restrict__ f4, unsigned short* __restrict__ f5)
{
    int b = blockIdx.x;
    const float* w; unsigned short* f; int CIN, NG, NCH, base;
    if (b < 9)        { w = w2; f = f2; CIN = 32;  NG = 4;  NCH = 1; base = 0;   }
    else if (b < 45)  { w = w3; f = f3; CIN = 64;  NG = 8;  NCH = 2; base = 9;   }
    else if (b < 189) { w = w4; f = f4; CIN = 128; NG = 16; NCH = 4; base = 45;  }
    else              { w = w5; f = f5; CIN = 256; NG = 16; NCH = 8; base = 189; }
    int idx = (b - base) * 256 + threadIdx.x;
    int lane = idx & 63, rest = idx >> 6;
    int c = rest % NCH; rest /= NCH;
    int g = rest % NG;  int t = rest / NG;
    if (t >= 9) return;
    int oc = g * 16 + (lane & 15);
    int cin0 = c * 32 + (lane >> 4) * 8;
    short8 v;
    #pragma unroll
    for (int j = 0; j < 8; ++j) {
        v[j] = (short)f2bf(w[((size_t)oc * CIN + cin0 + j) * 9 + t]);
    }
    *(short8*)&f[(size_t)idx * 8] = v;
}

// ================= MFMA conv: bf16 in (ch-last), tap-decomposed implicit GEMM =================
// block: 16 cols x TR=8 rows of conv output x OCB out-channels; 4 waves split rows (2 each).
// CSPLIT==1: fused bias+relu+pool2x2, bf16 ch-last out [Hc/2][Hc/2][COUT]
// CSPLIT>1 : raw f32 partial out [cs][COUT][Hc][Hc]
template<int CIN, int COUT, int Hc, int OCB, int CSPLIT>
__global__ __launch_bounds__(256) void conv_mfma(
    const unsigned short* __restrict__ in, const unsigned short* __restrict__ wfrag,
    const float* __restrict__ bias, void* __restrict__ outv)
{
    constexpr int TR = 8;
    constexpr int NOG = OCB / 16;
    constexpr int NG  = COUT / 16;
    constexpr int NCHT = CIN / 32;
    constexpr int NCH = NCHT / CSPLIT;
    constexpr int RPW = TR / 4;      // rows per wave = 2
    const int tid = threadIdx.x;
    const int lane = tid & 63, wid = tid >> 6;
    const int col = lane & 15, kgl = lane >> 4;
    const int X0 = blockIdx.x * 16, Y0 = blockIdx.y * TR;
    const int ob = blockIdx.z / CSPLIT, cs = blockIdx.z % CSPLIT;

    __shared__ __align__(16) unsigned short lds[(TR + 2) * 4 * 18 * 8];

    f32x4 acc[NOG][RPW];
    #pragma unroll
    for (int g = 0; g < NOG; ++g) {
        #pragma unroll
        for (int r = 0; r < RPW; ++r) {
            acc[g][r] = {0.f, 0.f, 0.f, 0.f};
        }
    }

    for (int cc = 0; cc < NCH; ++cc) {
        const int ca = cs * NCH + cc;
        __syncthreads();
        constexpr int ITEMS = (TR + 2) * 18 * 4;   // 720
        for (int i = tid; i < ITEMS; i += 256) {
            int kg = i & 3, rem = i >> 2;
            int hx = rem % 18, hy = rem / 18;
            int gy = Y0 + hy - 1, gx = X0 + hx - 1;
            short8 v = {0, 0, 0, 0, 0, 0, 0, 0};
            if (gy >= 0 && gy < Hc && gx >= 0 && gx < Hc) {
                v = *(const short8*)&in[((size_t)(gy * Hc + gx)) * CIN + ca * 32 + kg * 8];
            }
            *(short8*)&lds[((hy * 4 + kg) * 18 + hx) * 8] = v;
        }
        __syncthreads();
        #pragma unroll
        for (int t = 0; t < 9; ++t) {
            const int ky = t / 3, kx = t % 3;
            short8 af[NOG];
            #pragma unroll
            for (int g = 0; g < NOG; ++g) {
                af[g] = *(const short8*)&wfrag[((((size_t)t * NG + ob * NOG + g) * NCHT + ca) * 64 + lane) * 8];
            }
            #pragma unroll
            for (int r = 0; r < RPW; ++r) {
                const int py = wid * RPW + r;
                short8 bf = *(const short8*)&lds[(((py + ky) * 4 + kgl) * 18 + col + kx) * 8];
                #pragma unroll
                for (int g = 0; g < NOG; ++g) {
                    acc[g][r] = __builtin_amdgcn_mfma_f32_16x16x32_bf16(af[g], bf, acc[g][r], 0, 0, 0);
                }
            }
        }
    }

    if constexpr (CSPLIT == 1) {
        constexpr int Wp = Hc / 2;
        unsigned short* outp = (unsigned short*)outv;
        #pragma unroll
        for (int g = 0; g < NOG; ++g) {
            const int oc = (ob * NOG + g) * 16 + kgl * 4;
            const float4 bb = *(const float4*)&bias[oc];
            const float bbv[4] = {bb.x, bb.y, bb.z, bb.w};
            #pragma unroll
            for (int pr = 0; pr < RPW / 2; ++pr) {
                float vv[4];
                #pragma unroll
                for (int q = 0; q < 4; ++q) {
                    float v = fmaxf(acc[g][2 * pr][q], acc[g][2 * pr + 1][q]);
                    v = fmaxf(v, __shfl_xor(v, 1));
                    vv[q] = fmaxf(v + bbv[q], 0.f);
                }
                if (!(col & 1)) {
                    unsigned u0 = f2bf(vv[0]) | ((unsigned)f2bf(vv[1]) << 16);
                    unsigned u1 = f2bf(vv[2]) | ((unsigned)f2bf(vv[3]) << 16);
                    const int pry = Y0 / 2 + wid * (RPW / 2) + pr;
                    const int prx = X0 / 2 + (col >> 1);
                    uint2 uu; uu.x = u0; uu.y = u1;
                    *(uint2*)&outp[((size_t)(pry * Wp + prx)) * COUT + oc] = uu;
                }
            }
        }
    } else {
        float* po = (float*)outv;
        #pragma unroll
        for (int g = 0; g < NOG; ++g) {
            #pragma unroll
            for (int r = 0; r < RPW; ++r) {
                const int gy = Y0 + wid * RPW + r;
                #pragma unroll
                for (int q = 0; q < 4; ++q) {
                    const int oc = (ob * NOG + g) * 16 + kgl * 4 + q;
                    po[((size_t)(cs * COUT + oc) * Hc + gy) * Hc + X0 + col] = acc[g][r][q];
                }
            }
        }
    }
}

// sum CS pre-pool f32 partials, add bias, relu, 2x2 maxpool -> f32 channel-major out
template<int COUT, int HP, int CS>
__global__ void finalize_pool(const float* __restrict__ partial, const float* __restrict__ bias,
                              float* __restrict__ out)
{
    int idx = blockIdx.x * 256 + threadIdx.x;
    if (idx >= COUT * HP * HP) return;
    constexpr int H = HP * 2;
    int x = idx & (HP - 1); int rest = idx / HP;
    int y = rest & (HP - 1); int oc = rest / HP;
    float v00 = 0.f, v01 = 0.f, v10 = 0.f, v11 = 0.f;
    #pragma unroll
    for (int cs = 0; cs < CS; ++cs) {
        const float* p = partial + ((size_t)(cs * COUT + oc) * H + 2 * y) * H + 2 * x;
        v00 += p[0]; v01 += p[1]; v10 += p[H]; v11 += p[H + 1];
    }
    float m = fmaxf(fmaxf(v00, v01), fmaxf(v10, v11)) + bias[oc];
    out[idx] = fmaxf(m, 0.f);
}

// ============ graph tail (f32, unchanged from round 2) ============

__global__ void zero_kernel(float* p) { p[blockIdx.x * 256 + threadIdx.x] = 0.f; }

__global__ void adj_build_kernel(const int* __restrict__ src, const int* __restrict__ dst,
                                 float* adj, float* adjT)
{
    int e = blockIdx.x * 256 + threadIdx.x;
    int s = src[e], d = dst[e];
    atomicAdd(&adj[s * NN + d], 1.0f);
    atomicAdd(&adjT[d * NN + s], 1.0f);
}

__global__ void agg_kernel(const float* __restrict__ adjT, const float* __restrict__ org,
                           float* __restrict__ agg)
{
    int n = blockIdx.x, f = threadIdx.x;
    __shared__ float row[NN];
    __shared__ float red[256];
    float r = adjT[n * NN + f];
    row[f] = r; red[f] = r;
    __syncthreads();
    for (int s = 128; s > 0; s >>= 1) { if (f < s) red[f] += red[f + s]; __syncthreads(); }
    float cnt = red[0];
    float acc = 0.f;
    #pragma unroll 4
    for (int s = 0; s < NN; ++s) acc = fmaf(row[s], org[s * NN + f], acc);
    agg[n * NN + f] = (cnt > 0.f) ? acc / cnt : 0.f;
}

__global__ void sage1_lin_kernel(const float* __restrict__ agg, const float* __restrict__ org,
                                 const float* __restrict__ wl, const float* __restrict__ wr,
                                 const float* __restrict__ b, float* __restrict__ x1)
{
    int t = blockIdx.x * 256 + threadIdx.x;
    int n = t >> 1, p = t & 1;
    float acc = b[p];
    for (int k = 0; k < NN; ++k)
        acc += agg[n * NN + k] * wl[k * 2 + p] + org[n * NN + k] * wr[k * 2 + p];
    x1[n * 2 + p] = acc;
}

__global__ void sage2_lin_kernel(const float* __restrict__ agg, const float* __restrict__ org,
                                 const float* __restrict__ wl, const float* __restrict__ wr,
                                 const float* __restrict__ b, float* __restrict__ s_pre)
{
    int n = blockIdx.x, p = threadIdx.x;
    float acc = b[p];
    for (int k = 0; k < NN; ++k)
        acc += agg[n * NN + k] * wl[k * NC + p] + org[n * NN + k] * wr[k * NC + p];
    s_pre[n * NC + p] = acc;
}

__global__ void softmax_kernel(const float* __restrict__ s_pre, float* __restrict__ s_soft)
{
    int n = blockIdx.x, p = threadIdx.x;
    __shared__ float red[128];
    float v = s_pre[n * NC + p];
    red[p] = v; __syncthreads();
    for (int s = 64; s > 0; s >>= 1) { if (p < s) red[p] = fmaxf(red[p], red[p + s]); __syncthreads(); }
    float m = red[0]; __syncthreads();
    float e = expf(v - m);
    red[p] = e; __syncthreads();
    for (int s = 64; s > 0; s >>= 1) { if (p < s) red[p] += red[p + s]; __syncthreads(); }
    s_soft[n * NC + p] = e / red[0];
}

__global__ void ent_kernel(const float* __restrict__ s_soft, float* __restrict__ out)
{
    int t = threadIdx.x;
    float a = 0.f;
    for (int i = t; i < NN * NC; i += 256) { float p = s_soft[i]; a -= p * logf(p + 1e-15f); }
    __shared__ float red[256];
    red[t] = a; __syncthreads();
    for (int s = 128; s > 0; s >>= 1) { if (t < s) red[t] += red[t + s]; __syncthreads(); }
    if (t == 0) out[0] = red[0] / (float)NN;
}

__global__ void linkpart_kernel(const float* __restrict__ adj, const float* __restrict__ s_soft,
                                float* __restrict__ partial)
{
    int i = blockIdx.x, j = threadIdx.x;
    __shared__ float si[NC];
    if (j < NC) si[j] = s_soft[i * NC + j];
    __syncthreads();
    float dot = 0.f;
    for (int k = 0; k < NC; ++k) dot += si[k] * s_soft[j * NC + k];
    float d = adj[i * NN + j] - dot;
    float v = d * d;
    __shared__ float red[256];
    red[j] = v; __syncthreads();
    for (int s = 128; s > 0; s >>= 1) { if (j < s) red[j] += red[j + s]; __syncthreads(); }
    if (j == 0) partial[i] = red[0];
}

__global__ void linkfinal_kernel(const float* __restrict__ partial, float* __restrict__ out)
{
    int t = threadIdx.x;
    __shared__ float red[256];
    red[t] = partial[t]; __syncthreads();
    for (int s = 128; s > 0; s >>= 1) { if (t < s) red[t] += red[t + s]; __syncthreads(); }
    if (t == 0) out[0] = sqrtf(red[0]) / (float)(NN * NN);
}

__global__ void xpool_kernel(const float* __restrict__ s_soft, const float* __restrict__ x1,
                             float* __restrict__ nodes_ws, float* __restrict__ nodes_out)
{
    int t = threadIdx.x;
    int c = t >> 1, p = t & 1;
    float acc = 0.f;
    for (int n = 0; n < NN; ++n) acc += s_soft[n * NC + c] * x1[n * 2 + p];
    float nd = tanhf(acc);
    nodes_ws[c * 2 + p] = nd;
    nodes_out[c * 2 + p] = nd;
}

__global__ void adjT_mm_kernel(const float* __restrict__ adj, const float* __restrict__ s_soft,
                               float* __restrict__ T)
{
    int n = blockIdx.x, p = threadIdx.x;
    float acc = 0.f;
    for (int k = 0; k < NN; ++k) acc += adj[n * NN + k] * s_soft[k * NC + p];
    T[n * NC + p] = acc;
}

__global__ void adjpool_kernel(const float* __restrict__ s_soft, const float* __restrict__ T,
                               float* __restrict__ adj_pool)
{
    int c = blockIdx.x, p = threadIdx.x;
    float acc = 0.f;
    for (int n = 0; n < NN; ++n) acc += s_soft[n * NC + c] * T[n * NC + p];
    adj_pool[c * NC + p] = acc;
}

__global__ void edgebin_kernel(const float* __restrict__ adj_pool, float* __restrict__ eb)
{
    int c = blockIdx.x, p = threadIdx.x;
    __shared__ float red[128];
    float v = adj_pool[c * NC + p];
    red[p] = v; __syncthreads();
    for (int s = 64; s > 0; s >>= 1) { if (p < s) red[p] = fmaxf(red[p], red[p + s]); __syncthreads(); }
    eb[c * NC + p] = (v == red[0]) ? 1.f : 0.f;
}

__global__ void sage3_kernel(const float* __restrict__ eb, const float* __restrict__ nodes,
                             const float* __restrict__ wl, const float* __restrict__ wr,
                             const float* __restrict__ b, float* __restrict__ out)
{
    int j = threadIdx.x;
    float indeg = 0.f, a0 = 0.f, a1 = 0.f;
    for (int i = 0; i < NC; ++i) {
        float e = eb[i * NC + j];
        indeg += e;
        a0 += e * nodes[i * 2 + 0];
        a1 += e * nodes[i * 2 + 1];
    }
    float inv = (indeg > 0.f) ? 1.f / fmaxf(indeg, 1.f) : 0.f;
    float g0 = a0 * inv, g1 = a1 * inv;
    float n0 = nodes[j * 2 + 0], n1 = nodes[j * 2 + 1];
    out[j * 2 + 0] = g0 * wl[0] + g1 * wl[2] + b[0] + n0 * wr[0] + n1 * wr[2];
    out[j * 2 + 1] = g0 * wl[1] + g1 * wl[3] + b[1] + n0 * wr[1] + n1 * wr[3];
}

extern "C" void kernel_launch(void* const* d_in, const int* in_sizes, int n_in,
                              void* d_out, int out_size, void* d_ws, size_t ws_size,
                              hipStream_t stream)
{
    const float* input = (const float*)d_in[0];
    const int* eidx = (const int*)d_in[1];
    const int* src = eidx;
    const int* dst = eidx + NE;
    const float* w1 = (const float*)d_in[2];  const float* b1 = (const float*)d_in[3];
    const float* w2 = (const float*)d_in[4];  const float* b2 = (const float*)d_in[5];
    const float* w3 = (const float*)d_in[6];  const float* b3 = (const float*)d_in[7];
    const float* w4 = (const float*)d_in[8];  const float* b4 = (const float*)d_in[9];
    const float* w5 = (const float*)d_in[10]; const float* b5 = (const float*)d_in[11];
    const float* s1_wl = (const float*)d_in[12]; const float* s1_wr = (const float*)d_in[13];
    const float* s1_b  = (const float*)d_in[14];
    const float* s2_wl = (const float*)d_in[15]; const float* s2_wr = (const float*)d_in[16];
    const float* s2_b  = (const float*)d_in[17];
    const float* s3_wl = (const float*)d_in[18]; const float* s3_wr = (const float*)d_in[19];
    const float* s3_b  = (const float*)d_in[20];

    float* ws = (float*)d_ws;
    // region plan (float offsets):
    //  c1 bf16 [0,1048576)        (256*256*32 bf16 = 4MB)
    //  c2 bf16 [1048576,1572864)  (128*128*64 bf16 = 2MB)
    //  c3 bf16 [0,262144)         (c1 dead)
    //  c4 bf16 [1048576,1179648)  (c2 dead)
    //  P5 f32  [0,1048576)        (4*256*32*32, c3 dead)
    //  ORG f32 [1179648,1245184)
    //  wfrags  [1572864,2061312)
    //  graph   [2061312,2373632)
    unsigned short* c1 = (unsigned short*)(ws);
    unsigned short* c2 = (unsigned short*)(ws + 1048576);
    unsigned short* c3 = (unsigned short*)(ws);
    unsigned short* c4 = (unsigned short*)(ws + 1048576);
    float* P5  = ws;
    float* ORG = ws + 1179648;
    unsigned short* f2 = (unsigned short*)(ws + 1572864);
    unsigned short* f3 = (unsigned short*)(ws + 1582080);
    unsigned short* f4 = (unsigned short*)(ws + 1618944);
    unsigned short* f5 = (unsigned short*)(ws + 1766400);

    float* adj    = ws + 2061312;
    float* adjT   = ws + 2126848;
    float* agg    = ws + 2192384;
    float* s_pre  = ws + 2257920;
    float* s_soft = ws + 2290688;
    float* T      = ws + 2323456;
    float* adjp   = ws + 2356224;
    float* x1g    = ws + 2372608;
    float* nodesb = ws + 2373120;
    float* lpart  = ws + 2373376;

    float* fout = (float*)d_out;
    float* out_main  = fout;
    float* out_link  = fout + 256;
    float* out_ent   = fout + 257;
    float* out_nodes = fout + 258;
    float* out_eb    = fout + 514;

    wfrag_prep_all<<<477, 256, 0, stream>>>(w2, w3, w4, w5, f2, f3, f4, f5);
    conv1_kernel<<<dim3(32, 32), 256, 0, stream>>>(input, w1, b1, c1);
    conv_mfma<32,  64, 256, 64, 1><<<dim3(16, 32, 1),  256, 0, stream>>>(c1, f2, b2, c2);
    conv_mfma<64, 128, 128, 64, 1><<<dim3(8, 16, 2),   256, 0, stream>>>(c2, f3, b3, c3);
    conv_mfma<128, 256, 64, 32, 1><<<dim3(4, 8, 8),    256, 0, stream>>>(c3, f4, b4, c4);
    conv_mfma<256, 256, 32, 32, 4><<<dim3(2, 4, 32),   256, 0, stream>>>(c4, f5, b5, P5);
    finalize_pool<256, 16, 4><<<256, 256, 0, stream>>>(P5, b5, ORG);

    zero_kernel<<<512, 256, 0, stream>>>(adj);   // adj + adjT contiguous
    adj_build_kernel<<<16, 256, 0, stream>>>(src, dst, adj, adjT);
    agg_kernel<<<256, 256, 0, stream>>>(adjT, ORG, agg);
    sage1_lin_kernel<<<2, 256, 0, stream>>>(agg, ORG, s1_wl, s1_wr, s1_b, x1g);
    sage2_lin_kernel<<<256, 128, 0, stream>>>(agg, ORG, s2_wl, s2_wr, s2_b, s_pre);
    softmax_kernel<<<256, 128, 0, stream>>>(s_pre, s_soft);
    ent_kernel<<<1, 256, 0, stream>>>(s_soft, out_ent);
    linkpart_kernel<<<256, 256, 0, stream>>>(adj, s_soft, lpart);
    linkfinal_kernel<<<1, 256, 0, stream>>>(lpart, out_link);
    xpool_kernel<<<1, 256, 0, stream>>>(s_soft, x1g, nodesb, out_nodes);
    adjT_mm_kernel<<<256, 128, 0, stream>>>(adj, s_soft, T);
    adjpool_kernel<<<128, 128, 0, stream>>>(s_soft, T, adjp);
    edgebin_kernel<<<128, 128, 0, stream>>>(adjp, out_eb);
    sage3_kernel<<<1, 128, 0, stream>>>(out_eb, nodesb, s3_wl, s3_wr, s3_b, out_main);
}

// Round 5
// 180.805 us; speedup vs baseline: 4.0854x; 1.1401x over previous
//
#include <hip/hip_runtime.h>
#include <math.h>

#define NN 256
#define NE 4096
#define NC 128

using short8  = __attribute__((ext_vector_type(8))) short;
using short4v = __attribute__((ext_vector_type(4))) short;
using f32x4   = __attribute__((ext_vector_type(4))) float;

static __device__ __forceinline__ unsigned short f2bf(float x) {
    unsigned u = __float_as_uint(x);
    unsigned r = (u + 0x7FFF + ((u >> 16) & 1)) >> 16;   // RNE
    return (unsigned short)r;
}

// ================= weight pre-fragmentation (all 5 convs in one kernel) =================
// convs 2-5 layout: [t(9)][g(COUT/16)][c(CIN/32)][lane(64)][8]; A-frag oc=lane&15, k=(lane>>4)*8+j
// conv1 layout: [slot(2)][g(2)][lane(64)][8]; slot0: k=tap*4+ch (taps 0-7), slot1: k=ch (tap 8)
__global__ void wfrag_prep_all(const float* __restrict__ w1, const float* __restrict__ w2,
                               const float* __restrict__ w3, const float* __restrict__ w4,
                               const float* __restrict__ w5,
                               unsigned short* __restrict__ f1, unsigned short* __restrict__ f2,
                               unsigned short* __restrict__ f3, unsigned short* __restrict__ f4,
                               unsigned short* __restrict__ f5)
{
    int b = blockIdx.x;
    if (b == 477) {   // conv1 frags: 256 threads = 2 slots x 2 og x 64 lanes
        int idx = threadIdx.x;
        int lane = idx & 63, rest = idx >> 6;
        int g = rest & 1, slot = rest >> 1;
        int oc = g * 16 + (lane & 15);
        short8 v;
        #pragma unroll
        for (int j = 0; j < 8; ++j) {
            int k = (lane >> 4) * 8 + j;
            float wv = 0.f;
            if (slot == 0) {
                int tap = k >> 2, ch = k & 3;
                if (ch < 3) wv = w1[oc * 27 + ch * 9 + tap];
            } else {
                if (k < 3) wv = w1[oc * 27 + k * 9 + 8];
            }
            v[j] = (short)f2bf(wv);
        }
        *(short8*)&f1[(size_t)idx * 8] = v;
        return;
    }
    const float* w; unsigned short* f; int CIN, NG, NCH, base;
    if (b < 9)        { w = w2; f = f2; CIN = 32;  NG = 4;  NCH = 1; base = 0;   }
    else if (b < 45)  { w = w3; f = f3; CIN = 64;  NG = 8;  NCH = 2; base = 9;   }
    else if (b < 189) { w = w4; f = f4; CIN = 128; NG = 16; NCH = 4; base = 45;  }
    else              { w = w5; f = f5; CIN = 256; NG = 16; NCH = 8; base = 189; }
    int idx = (b - base) * 256 + threadIdx.x;
    int lane = idx & 63, rest = idx >> 6;
    int c = rest % NCH; rest /= NCH;
    int g = rest % NG;  int t = rest / NG;
    if (t >= 9) return;
    int oc = g * 16 + (lane & 15);
    int cin0 = c * 32 + (lane >> 4) * 8;
    short8 v;
    #pragma unroll
    for (int j = 0; j < 8; ++j) {
        v[j] = (short)f2bf(w[((size_t)oc * CIN + cin0 + j) * 9 + t]);
    }
    *(short8*)&f[(size_t)idx * 8] = v;
}

// ================= conv1 MFMA: f32 NCHW 3x512x512 -> pooled ch-last bf16 [256][256][32] ===
// K=32 packed as 8 taps x 4 ch (3 real + pad); slot1 handles tap 8.
__global__ __launch_bounds__(256) void conv1_mfma(
    const float* __restrict__ in, const unsigned short* __restrict__ wf1,
    const float* __restrict__ bias, unsigned short* __restrict__ out)
{
    constexpr int Hc = 512, TR = 8;
    const int tid = threadIdx.x;
    const int lane = tid & 63, wid = tid >> 6;
    const int col = lane & 15, kgl = lane >> 4;
    const int X0 = blockIdx.x * 16, Y0 = blockIdx.y * TR;
    __shared__ __align__(16) unsigned short lds[10][18][4];
    if (tid < 180) {
        int hy = tid / 18, hx = tid - hy * 18;
        int gy = Y0 + hy - 1, gx = X0 + hx - 1;
        float v0 = 0.f, v1 = 0.f, v2 = 0.f;
        if (gy >= 0 && gy < Hc && gx >= 0 && gx < Hc) {
            v0 = in[0 * 262144 + gy * 512 + gx];
            v1 = in[1 * 262144 + gy * 512 + gx];
            v2 = in[2 * 262144 + gy * 512 + gx];
        }
        uint2 uu;
        uu.x = f2bf(v0) | ((unsigned)f2bf(v1) << 16);
        uu.y = f2bf(v2);
        *(uint2*)&lds[hy][hx][0] = uu;
    }
    short8 af[2][2];
    #pragma unroll
    for (int slot = 0; slot < 2; ++slot) {
        #pragma unroll
        for (int g = 0; g < 2; ++g) {
            af[slot][g] = *(const short8*)&wf1[((size_t)((slot * 2 + g) * 64 + lane)) * 8];
        }
    }
    __syncthreads();
    f32x4 acc[2][2];
    #pragma unroll
    for (int g = 0; g < 2; ++g) {
        #pragma unroll
        for (int r = 0; r < 2; ++r) acc[g][r] = {0.f, 0.f, 0.f, 0.f};
    }
    const int t0 = 2 * kgl, t1 = 2 * kgl + 1;
    const int dy0 = t0 / 3, dx0 = t0 % 3, dy1 = t1 / 3, dx1 = t1 % 3;
    #pragma unroll
    for (int r = 0; r < 2; ++r) {
        const int py = wid * 2 + r;
        short4v lo = *(const short4v*)&lds[py + dy0][col + dx0][0];
        short4v hi = *(const short4v*)&lds[py + dy1][col + dx1][0];
        short8 bf0 = __builtin_shufflevector(lo, hi, 0, 1, 2, 3, 4, 5, 6, 7);
        short4v z4 = {0, 0, 0, 0};
        short4v t8 = z4;
        if (kgl == 0) t8 = *(const short4v*)&lds[py + 2][col + 2][0];
        short8 bf1 = __builtin_shufflevector(t8, z4, 0, 1, 2, 3, 4, 5, 6, 7);
        #pragma unroll
        for (int g = 0; g < 2; ++g) {
            acc[g][r] = __builtin_amdgcn_mfma_f32_16x16x32_bf16(af[0][g], bf0, acc[g][r], 0, 0, 0);
            acc[g][r] = __builtin_amdgcn_mfma_f32_16x16x32_bf16(af[1][g], bf1, acc[g][r], 0, 0, 0);
        }
    }
    #pragma unroll
    for (int g = 0; g < 2; ++g) {
        const int oc = g * 16 + kgl * 4;
        const float4 bb = *(const float4*)&bias[oc];
        const float bbv[4] = {bb.x, bb.y, bb.z, bb.w};
        float vv[4];
        #pragma unroll
        for (int q = 0; q < 4; ++q) {
            float v = fmaxf(acc[g][0][q], acc[g][1][q]);
            v = fmaxf(v, __shfl_xor(v, 1));
            vv[q] = fmaxf(v + bbv[q], 0.f);
        }
        if (!(col & 1)) {
            unsigned u0 = f2bf(vv[0]) | ((unsigned)f2bf(vv[1]) << 16);
            unsigned u1 = f2bf(vv[2]) | ((unsigned)f2bf(vv[3]) << 16);
            const int pry = Y0 / 2 + wid;
            const int prx = X0 / 2 + (col >> 1);
            uint2 uu; uu.x = u0; uu.y = u1;
            *(uint2*)&out[((size_t)(pry * 256 + prx)) * 32 + oc] = uu;
        }
    }
}

// ================= MFMA conv (convs 2-5, unchanged from round 4) =================
template<int CIN, int COUT, int Hc, int OCB, int CSPLIT>
__global__ __launch_bounds__(256) void conv_mfma(
    const unsigned short* __restrict__ in, const unsigned short* __restrict__ wfrag,
    const float* __restrict__ bias, void* __restrict__ outv)
{
    constexpr int TR = 8;
    constexpr int NOG = OCB / 16;
    constexpr int NG  = COUT / 16;
    constexpr int NCHT = CIN / 32;
    constexpr int NCH = NCHT / CSPLIT;
    constexpr int RPW = TR / 4;
    const int tid = threadIdx.x;
    const int lane = tid & 63, wid = tid >> 6;
    const int col = lane & 15, kgl = lane >> 4;
    const int X0 = blockIdx.x * 16, Y0 = blockIdx.y * TR;
    const int ob = blockIdx.z / CSPLIT, cs = blockIdx.z % CSPLIT;

    __shared__ __align__(16) unsigned short lds[(TR + 2) * 4 * 18 * 8];

    f32x4 acc[NOG][RPW];
    #pragma unroll
    for (int g = 0; g < NOG; ++g) {
        #pragma unroll
        for (int r = 0; r < RPW; ++r) acc[g][r] = {0.f, 0.f, 0.f, 0.f};
    }

    for (int cc = 0; cc < NCH; ++cc) {
        const int ca = cs * NCH + cc;
        __syncthreads();
        constexpr int ITEMS = (TR + 2) * 18 * 4;
        for (int i = tid; i < ITEMS; i += 256) {
            int kg = i & 3, rem = i >> 2;
            int hx = rem % 18, hy = rem / 18;
            int gy = Y0 + hy - 1, gx = X0 + hx - 1;
            short8 v = {0, 0, 0, 0, 0, 0, 0, 0};
            if (gy >= 0 && gy < Hc && gx >= 0 && gx < Hc) {
                v = *(const short8*)&in[((size_t)(gy * Hc + gx)) * CIN + ca * 32 + kg * 8];
            }
            *(short8*)&lds[((hy * 4 + kg) * 18 + hx) * 8] = v;
        }
        __syncthreads();
        #pragma unroll
        for (int t = 0; t < 9; ++t) {
            const int ky = t / 3, kx = t % 3;
            short8 af[NOG];
            #pragma unroll
            for (int g = 0; g < NOG; ++g) {
                af[g] = *(const short8*)&wfrag[((((size_t)t * NG + ob * NOG + g) * NCHT + ca) * 64 + lane) * 8];
            }
            #pragma unroll
            for (int r = 0; r < RPW; ++r) {
                const int py = wid * RPW + r;
                short8 bf = *(const short8*)&lds[(((py + ky) * 4 + kgl) * 18 + col + kx) * 8];
                #pragma unroll
                for (int g = 0; g < NOG; ++g) {
                    acc[g][r] = __builtin_amdgcn_mfma_f32_16x16x32_bf16(af[g], bf, acc[g][r], 0, 0, 0);
                }
            }
        }
    }

    if constexpr (CSPLIT == 1) {
        constexpr int Wp = Hc / 2;
        unsigned short* outp = (unsigned short*)outv;
        #pragma unroll
        for (int g = 0; g < NOG; ++g) {
            const int oc = (ob * NOG + g) * 16 + kgl * 4;
            const float4 bb = *(const float4*)&bias[oc];
            const float bbv[4] = {bb.x, bb.y, bb.z, bb.w};
            #pragma unroll
            for (int pr = 0; pr < RPW / 2; ++pr) {
                float vv[4];
                #pragma unroll
                for (int q = 0; q < 4; ++q) {
                    float v = fmaxf(acc[g][2 * pr][q], acc[g][2 * pr + 1][q]);
                    v = fmaxf(v, __shfl_xor(v, 1));
                    vv[q] = fmaxf(v + bbv[q], 0.f);
                }
                if (!(col & 1)) {
                    unsigned u0 = f2bf(vv[0]) | ((unsigned)f2bf(vv[1]) << 16);
                    unsigned u1 = f2bf(vv[2]) | ((unsigned)f2bf(vv[3]) << 16);
                    const int pry = Y0 / 2 + wid * (RPW / 2) + pr;
                    const int prx = X0 / 2 + (col >> 1);
                    uint2 uu; uu.x = u0; uu.y = u1;
                    *(uint2*)&outp[((size_t)(pry * Wp + prx)) * COUT + oc] = uu;
                }
            }
        }
    } else {
        float* po = (float*)outv;
        #pragma unroll
        for (int g = 0; g < NOG; ++g) {
            #pragma unroll
            for (int r = 0; r < RPW; ++r) {
                const int gy = Y0 + wid * RPW + r;
                #pragma unroll
                for (int q = 0; q < 4; ++q) {
                    const int oc = (ob * NOG + g) * 16 + kgl * 4 + q;
                    po[((size_t)(cs * COUT + oc) * Hc + gy) * Hc + X0 + col] = acc[g][r][q];
                }
            }
        }
    }
}

// sum CS pre-pool f32 partials, add bias, relu, 2x2 maxpool -> f32 channel-major out
template<int COUT, int HP, int CS>
__global__ void finalize_pool(const float* __restrict__ partial, const float* __restrict__ bias,
                              float* __restrict__ out)
{
    int idx = blockIdx.x * 256 + threadIdx.x;
    if (idx >= COUT * HP * HP) return;
    constexpr int H = HP * 2;
    int x = idx & (HP - 1); int rest = idx / HP;
    int y = rest & (HP - 1); int oc = rest / HP;
    float v00 = 0.f, v01 = 0.f, v10 = 0.f, v11 = 0.f;
    #pragma unroll
    for (int cs = 0; cs < CS; ++cs) {
        const float* p = partial + ((size_t)(cs * COUT + oc) * H + 2 * y) * H + 2 * x;
        v00 += p[0]; v01 += p[1]; v10 += p[H]; v11 += p[H + 1];
    }
    float m = fmaxf(fmaxf(v00, v01), fmaxf(v10, v11)) + bias[oc];
    out[idx] = fmaxf(m, 0.f);
}

// ============ fused graph tail ============

__global__ void zero_kernel(float* p) { p[blockIdx.x * 256 + threadIdx.x] = 0.f; }

__global__ void adj_build_kernel(const int* __restrict__ src, const int* __restrict__ dst,
                                 float* adj, float* adjT)
{
    int e = blockIdx.x * 256 + threadIdx.x;
    int s = src[e], d = dst[e];
    atomicAdd(&adj[s * NN + d], 1.0f);   // sums of 1.0 are order-exact
    atomicAdd(&adjT[d * NN + s], 1.0f);
}

// per-node: agg + sage1 + sage2 + softmax + entropy partial. block n, 256 threads.
__global__ __launch_bounds__(256) void node_fused_kernel(
    const float* __restrict__ adjT, const float* __restrict__ org,
    const float* __restrict__ s1wl, const float* __restrict__ s1wr, const float* __restrict__ s1b,
    const float* __restrict__ s2wl, const float* __restrict__ s2wr, const float* __restrict__ s2b,
    float* __restrict__ s_soft, float* __restrict__ x1g, float* __restrict__ entp)
{
    int n = blockIdx.x, t = threadIdx.x;
    __shared__ float rowT[256], orgn[256], aggn[256], red[256], sm[128];
    float rT = adjT[n * 256 + t];
    rowT[t] = rT; orgn[t] = org[n * 256 + t]; red[t] = rT;
    __syncthreads();
    for (int s = 128; s > 0; s >>= 1) { if (t < s) red[t] += red[t + s]; __syncthreads(); }
    float cnt = red[0];
    float acc = 0.f;
    for (int s = 0; s < 256; ++s) acc = fmaf(rowT[s], org[s * 256 + t], acc);
    float aggv = (cnt > 0.f) ? acc / cnt : 0.f;
    aggn[t] = aggv;
    __syncthreads();
    // x1 (2 outputs)
    float v0 = aggv * s1wl[t * 2 + 0] + orgn[t] * s1wr[t * 2 + 0];
    float v1 = aggv * s1wl[t * 2 + 1] + orgn[t] * s1wr[t * 2 + 1];
    red[t] = v0; __syncthreads();
    for (int s = 128; s > 0; s >>= 1) { if (t < s) red[t] += red[t + s]; __syncthreads(); }
    float x10 = red[0] + s1b[0];
    __syncthreads();
    red[t] = v1; __syncthreads();
    for (int s = 128; s > 0; s >>= 1) { if (t < s) red[t] += red[t + s]; __syncthreads(); }
    float x11 = red[0] + s1b[1];
    if (t == 0) { x1g[n * 2 + 0] = x10; x1g[n * 2 + 1] = x11; }
    __syncthreads();
    // s_pre half-split: p = t&127, h = t>>7
    int p = t & 127, h = t >> 7;
    float a2 = 0.f;
    for (int k = h * 128; k < h * 128 + 128; ++k) {
        a2 += aggn[k] * s2wl[k * NC + p] + orgn[k] * s2wr[k * NC + p];
    }
    red[t] = a2; __syncthreads();
    if (t < 128) sm[p] = red[t] + red[t + 128] + s2b[p];
    __syncthreads();
    if (t < 128) red[t] = sm[t];
    __syncthreads();
    for (int s = 64; s > 0; s >>= 1) { if (t < s) red[t] = fmaxf(red[t], red[t + s]); __syncthreads(); }
    float mx = red[0];
    __syncthreads();
    float e = 0.f;
    if (t < 128) { e = expf(sm[t] - mx); red[t] = e; } else { red[t] = 0.f; }
    __syncthreads();
    for (int s = 64; s > 0; s >>= 1) { if (t < s) red[t] += red[t + s]; __syncthreads(); }
    float denom = red[0];
    float q = e / denom;
    if (t < 128) s_soft[n * NC + t] = q;
    float ev = (t < 128) ? -q * logf(q + 1e-15f) : 0.f;
    __syncthreads();
    red[t] = ev; __syncthreads();
    for (int s = 128; s > 0; s >>= 1) { if (t < s) red[t] += red[t + s]; __syncthreads(); }
    if (t == 0) entp[n] = red[0];
}

// per-row i: link partial + T = adj @ s_soft. block i, 256 threads.
__global__ __launch_bounds__(256) void row_fused_kernel(
    const float* __restrict__ adj, const float* __restrict__ s_soft,
    float* __restrict__ T, float* __restrict__ lpart)
{
    int i = blockIdx.x, j = threadIdx.x;
    __shared__ float si[NC], adjrow[256], red[256];
    adjrow[j] = adj[i * 256 + j];
    if (j < NC) si[j] = s_soft[i * NC + j];
    __syncthreads();
    float dot = 0.f;
    for (int k = 0; k < NC; ++k) dot = fmaf(si[k], s_soft[j * NC + k], dot);
    float d = adjrow[j] - dot;
    red[j] = d * d; __syncthreads();
    for (int s = 128; s > 0; s >>= 1) { if (j < s) red[j] += red[j + s]; __syncthreads(); }
    if (j == 0) lpart[i] = red[0];
    int p = j & 127, h = j >> 7;
    float a = 0.f;
    for (int k = h * 128; k < h * 128 + 128; ++k) a = fmaf(adjrow[k], s_soft[k * NC + p], a);
    __syncthreads();
    red[j] = a; __syncthreads();
    if (j < 128) T[i * NC + p] = red[j] + red[j + 128];
}

// per-cluster c: adj_pool row + argmax binarize + xpool/tanh. block c, 256 threads.
__global__ __launch_bounds__(256) void cluster_fused_kernel(
    const float* __restrict__ s_soft, const float* __restrict__ T, const float* __restrict__ x1g,
    float* __restrict__ eb_out, float* __restrict__ nodes_out)
{
    int c = blockIdx.x, t = threadIdx.x;
    __shared__ float colc[256], red[256], ap[NC];
    colc[t] = s_soft[t * NC + c];
    __syncthreads();
    int p = t & 127, h = t >> 7;
    float a = 0.f;
    for (int n = h * 128; n < h * 128 + 128; ++n) a = fmaf(colc[n], T[n * NC + p], a);
    red[t] = a; __syncthreads();
    if (t < 128) ap[t] = red[t] + red[t + 128];
    __syncthreads();
    if (t < 128) red[t] = ap[t];
    __syncthreads();
    for (int s = 64; s > 0; s >>= 1) { if (t < s) red[t] = fmaxf(red[t], red[t + s]); __syncthreads(); }
    float mx = red[0];
    if (t < 128) eb_out[c * NC + t] = (ap[t] == mx) ? 1.f : 0.f;
    __syncthreads();
    float w0 = colc[t] * x1g[t * 2 + 0];
    float w1 = colc[t] * x1g[t * 2 + 1];
    red[t] = w0; __syncthreads();
    for (int s = 128; s > 0; s >>= 1) { if (t < s) red[t] += red[t + s]; __syncthreads(); }
    float n0 = tanhf(red[0]);
    __syncthreads();
    red[t] = w1; __syncthreads();
    for (int s = 128; s > 0; s >>= 1) { if (t < s) red[t] += red[t + s]; __syncthreads(); }
    float n1 = tanhf(red[0]);
    if (t == 0) { nodes_out[c * 2 + 0] = n0; nodes_out[c * 2 + 1] = n1; }
}

// final: link norm + ent mean + sage3. 1 block, 256 threads.
__global__ __launch_bounds__(256) void final_kernel(
    const float* __restrict__ lpart, const float* __restrict__ entp,
    const float* __restrict__ eb, const float* __restrict__ nodes,
    const float* __restrict__ wl, const float* __restrict__ wr, const float* __restrict__ b,
    float* __restrict__ out_main, float* __restrict__ out_link, float* __restrict__ out_ent)
{
    int t = threadIdx.x;
    __shared__ float red[256];
    red[t] = lpart[t]; __syncthreads();
    for (int s = 128; s > 0; s >>= 1) { if (t < s) red[t] += red[t + s]; __syncthreads(); }
    if (t == 0) out_link[0] = sqrtf(red[0]) / (float)(NN * NN);
    __syncthreads();
    red[t] = entp[t]; __syncthreads();
    for (int s = 128; s > 0; s >>= 1) { if (t < s) red[t] += red[t + s]; __syncthreads(); }
    if (t == 0) out_ent[0] = red[0] / (float)NN;
    if (t < NC) {
        int j = t;
        float indeg = 0.f, a0 = 0.f, a1 = 0.f;
        for (int i2 = 0; i2 < NC; ++i2) {
            float e = eb[i2 * NC + j];
            indeg += e;
            a0 += e * nodes[i2 * 2 + 0];
            a1 += e * nodes[i2 * 2 + 1];
        }
        float inv = (indeg > 0.f) ? 1.f / fmaxf(indeg, 1.f) : 0.f;
        float g0 = a0 * inv, g1 = a1 * inv;
        float n0 = nodes[j * 2 + 0], n1 = nodes[j * 2 + 1];
        out_main[j * 2 + 0] = g0 * wl[0] + g1 * wl[2] + b[0] + n0 * wr[0] + n1 * wr[2];
        out_main[j * 2 + 1] = g0 * wl[1] + g1 * wl[3] + b[1] + n0 * wr[1] + n1 * wr[3];
    }
}

extern "C" void kernel_launch(void* const* d_in, const int* in_sizes, int n_in,
                              void* d_out, int out_size, void* d_ws, size_t ws_size,
                              hipStream_t stream)
{
    const float* input = (const float*)d_in[0];
    const int* eidx = (const int*)d_in[1];
    const int* src = eidx;
    const int* dst = eidx + NE;
    const float* w1 = (const float*)d_in[2];  const float* b1 = (const float*)d_in[3];
    const float* w2 = (const float*)d_in[4];  const float* b2 = (const float*)d_in[5];
    const float* w3 = (const float*)d_in[6];  const float* b3 = (const float*)d_in[7];
    const float* w4 = (const float*)d_in[8];  const float* b4 = (const float*)d_in[9];
    const float* w5 = (const float*)d_in[10]; const float* b5 = (const float*)d_in[11];
    const float* s1_wl = (const float*)d_in[12]; const float* s1_wr = (const float*)d_in[13];
    const float* s1_b  = (const float*)d_in[14];
    const float* s2_wl = (const float*)d_in[15]; const float* s2_wr = (const float*)d_in[16];
    const float* s2_b  = (const float*)d_in[17];
    const float* s3_wl = (const float*)d_in[18]; const float* s3_wr = (const float*)d_in[19];
    const float* s3_b  = (const float*)d_in[20];

    float* ws = (float*)d_ws;
    // region plan (float offsets):
    //  c1 bf16 [0,1048576)        c3 bf16 aliases [0,262144)     P5 f32 [0,1048576)
    //  c2 bf16 [1048576,1572864)  c4 bf16 aliases [1048576,1179648)
    //  ORG f32 [1179648,1245184)
    //  f1 [1572864,1573888) f2 [1573888,1583104) f3 [1583104,1619968)
    //  f4 [1619968,1767424) f5 [1767424,2062336)
    //  adj [2062336,2127872) adjT [2127872,2193408) s_soft [2193408,2226176)
    //  T [2226176,2258944) x1g [2258944,2259456) lpart [2259456,2259712) entp [2259712,2259968)
    unsigned short* c1 = (unsigned short*)(ws);
    unsigned short* c2 = (unsigned short*)(ws + 1048576);
    unsigned short* c3 = (unsigned short*)(ws);
    unsigned short* c4 = (unsigned short*)(ws + 1048576);
    float* P5  = ws;
    float* ORG = ws + 1179648;
    unsigned short* f1 = (unsigned short*)(ws + 1572864);
    unsigned short* f2 = (unsigned short*)(ws + 1573888);
    unsigned short* f3 = (unsigned short*)(ws + 1583104);
    unsigned short* f4 = (unsigned short*)(ws + 1619968);
    unsigned short* f5 = (unsigned short*)(ws + 1767424);
    float* adj    = ws + 2062336;
    float* adjT   = ws + 2127872;
    float* s_soft = ws + 2193408;
    float* T      = ws + 2226176;
    float* x1g    = ws + 2258944;
    float* lpart  = ws + 2259456;
    float* entp   = ws + 2259712;

    float* fout = (float*)d_out;
    float* out_main  = fout;
    float* out_link  = fout + 256;
    float* out_ent   = fout + 257;
    float* out_nodes = fout + 258;
    float* out_eb    = fout + 514;

    wfrag_prep_all<<<478, 256, 0, stream>>>(w1, w2, w3, w4, w5, f1, f2, f3, f4, f5);
    zero_kernel<<<512, 256, 0, stream>>>(adj);   // adj + adjT contiguous (131072 floats)
    adj_build_kernel<<<16, 256, 0, stream>>>(src, dst, adj, adjT);

    conv1_mfma<<<dim3(32, 64), 256, 0, stream>>>(input, f1, b1, c1);
    conv_mfma<32,  64, 256, 64, 1><<<dim3(16, 32, 1), 256, 0, stream>>>(c1, f2, b2, c2);
    conv_mfma<64, 128, 128, 64, 1><<<dim3(8, 16, 2),  256, 0, stream>>>(c2, f3, b3, c3);
    conv_mfma<128, 256, 64, 32, 1><<<dim3(4, 8, 8),   256, 0, stream>>>(c3, f4, b4, c4);
    conv_mfma<256, 256, 32, 32, 4><<<dim3(2, 4, 32),  256, 0, stream>>>(c4, f5, b5, P5);
    finalize_pool<256, 16, 4><<<256, 256, 0, stream>>>(P5, b5, ORG);

    node_fused_kernel<<<256, 256, 0, stream>>>(adjT, ORG, s1_wl, s1_wr, s1_b,
                                               s2_wl, s2_wr, s2_b, s_soft, x1g, entp);
    row_fused_kernel<<<256, 256, 0, stream>>>(adj, s_soft, T, lpart);
    cluster_fused_kernel<<<128, 256, 0, stream>>>(s_soft, T, x1g, out_eb, out_nodes);
    final_kernel<<<1, 256, 0, stream>>>(lpart, entp, out_eb, out_nodes,
                                        s3_wl, s3_wr, s3_b, out_main, out_link, out_ent);
}

// Round 6
// 111.844 us; speedup vs baseline: 6.6044x; 1.6166x over previous
//
#include <hip/hip_runtime.h>
#include <math.h>

#define NN 256
#define NE 4096
#define NC 128

using short8  = __attribute__((ext_vector_type(8))) short;
using short4v = __attribute__((ext_vector_type(4))) short;
using f32x4   = __attribute__((ext_vector_type(4))) float;

static __device__ __forceinline__ unsigned short f2bf(float x) {
    unsigned u = __float_as_uint(x);
    unsigned r = (u + 0x7FFF + ((u >> 16) & 1)) >> 16;   // RNE
    return (unsigned short)r;
}

// wave shfl reduce + cross-wave combine (256 threads). red4 is 4-float LDS scratch.
static __device__ __forceinline__ float block_sum_256(float v, float* red4) {
    #pragma unroll
    for (int o = 32; o > 0; o >>= 1) v += __shfl_xor(v, o);
    __syncthreads();                        // protect red4 against previous use
    if ((threadIdx.x & 63) == 0) red4[threadIdx.x >> 6] = v;
    __syncthreads();
    return (red4[0] + red4[1]) + (red4[2] + red4[3]);
}

// ================= weight pre-fragmentation (all 5 convs in one kernel) =================
__global__ void wfrag_prep_all(const float* __restrict__ w1, const float* __restrict__ w2,
                               const float* __restrict__ w3, const float* __restrict__ w4,
                               const float* __restrict__ w5,
                               unsigned short* __restrict__ f1, unsigned short* __restrict__ f2,
                               unsigned short* __restrict__ f3, unsigned short* __restrict__ f4,
                               unsigned short* __restrict__ f5)
{
    int b = blockIdx.x;
    if (b == 477) {   // conv1 frags: 256 threads = 2 slots x 2 og x 64 lanes
        int idx = threadIdx.x;
        int lane = idx & 63, rest = idx >> 6;
        int g = rest & 1, slot = rest >> 1;
        int oc = g * 16 + (lane & 15);
        short8 v;
        #pragma unroll
        for (int j = 0; j < 8; ++j) {
            int k = (lane >> 4) * 8 + j;
            float wv = 0.f;
            if (slot == 0) {
                int tap = k >> 2, ch = k & 3;
                if (ch < 3) wv = w1[oc * 27 + ch * 9 + tap];
            } else {
                if (k < 3) wv = w1[oc * 27 + k * 9 + 8];
            }
            v[j] = (short)f2bf(wv);
        }
        *(short8*)&f1[(size_t)idx * 8] = v;
        return;
    }
    const float* w; unsigned short* f; int CIN, NG, NCH, base;
    if (b < 9)        { w = w2; f = f2; CIN = 32;  NG = 4;  NCH = 1; base = 0;   }
    else if (b < 45)  { w = w3; f = f3; CIN = 64;  NG = 8;  NCH = 2; base = 9;   }
    else if (b < 189) { w = w4; f = f4; CIN = 128; NG = 16; NCH = 4; base = 45;  }
    else              { w = w5; f = f5; CIN = 256; NG = 16; NCH = 8; base = 189; }
    int idx = (b - base) * 256 + threadIdx.x;
    int lane = idx & 63, rest = idx >> 6;
    int c = rest % NCH; rest /= NCH;
    int g = rest % NG;  int t = rest / NG;
    if (t >= 9) return;
    int oc = g * 16 + (lane & 15);
    int cin0 = c * 32 + (lane >> 4) * 8;
    short8 v;
    #pragma unroll
    for (int j = 0; j < 8; ++j) {
        v[j] = (short)f2bf(w[((size_t)oc * CIN + cin0 + j) * 9 + t]);
    }
    *(short8*)&f[(size_t)idx * 8] = v;
}

// ================= conv1 MFMA: f32 NCHW 3x512x512 -> pooled ch-last bf16 [256][256][32] ===
__global__ __launch_bounds__(256) void conv1_mfma(
    const float* __restrict__ in, const unsigned short* __restrict__ wf1,
    const float* __restrict__ bias, unsigned short* __restrict__ out)
{
    constexpr int Hc = 512, TR = 8;
    const int tid = threadIdx.x;
    const int lane = tid & 63, wid = tid >> 6;
    const int col = lane & 15, kgl = lane >> 4;
    const int X0 = blockIdx.x * 16, Y0 = blockIdx.y * TR;
    __shared__ __align__(16) unsigned short lds[10][18][4];
    if (tid < 180) {
        int hy = tid / 18, hx = tid - hy * 18;
        int gy = Y0 + hy - 1, gx = X0 + hx - 1;
        float v0 = 0.f, v1 = 0.f, v2 = 0.f;
        if (gy >= 0 && gy < Hc && gx >= 0 && gx < Hc) {
            v0 = in[0 * 262144 + gy * 512 + gx];
            v1 = in[1 * 262144 + gy * 512 + gx];
            v2 = in[2 * 262144 + gy * 512 + gx];
        }
        uint2 uu;
        uu.x = f2bf(v0) | ((unsigned)f2bf(v1) << 16);
        uu.y = f2bf(v2);
        *(uint2*)&lds[hy][hx][0] = uu;
    }
    short8 af[2][2];
    #pragma unroll
    for (int slot = 0; slot < 2; ++slot) {
        #pragma unroll
        for (int g = 0; g < 2; ++g) {
            af[slot][g] = *(const short8*)&wf1[((size_t)((slot * 2 + g) * 64 + lane)) * 8];
        }
    }
    __syncthreads();
    f32x4 acc[2][2];
    #pragma unroll
    for (int g = 0; g < 2; ++g) {
        #pragma unroll
        for (int r = 0; r < 2; ++r) acc[g][r] = {0.f, 0.f, 0.f, 0.f};
    }
    const int t0 = 2 * kgl, t1 = 2 * kgl + 1;
    const int dy0 = t0 / 3, dx0 = t0 % 3, dy1 = t1 / 3, dx1 = t1 % 3;
    #pragma unroll
    for (int r = 0; r < 2; ++r) {
        const int py = wid * 2 + r;
        short4v lo = *(const short4v*)&lds[py + dy0][col + dx0][0];
        short4v hi = *(const short4v*)&lds[py + dy1][col + dx1][0];
        short8 bf0 = __builtin_shufflevector(lo, hi, 0, 1, 2, 3, 4, 5, 6, 7);
        short4v z4 = {0, 0, 0, 0};
        short4v t8 = z4;
        if (kgl == 0) t8 = *(const short4v*)&lds[py + 2][col + 2][0];
        short8 bf1 = __builtin_shufflevector(t8, z4, 0, 1, 2, 3, 4, 5, 6, 7);
        #pragma unroll
        for (int g = 0; g < 2; ++g) {
            acc[g][r] = __builtin_amdgcn_mfma_f32_16x16x32_bf16(af[0][g], bf0, acc[g][r], 0, 0, 0);
            acc[g][r] = __builtin_amdgcn_mfma_f32_16x16x32_bf16(af[1][g], bf1, acc[g][r], 0, 0, 0);
        }
    }
    #pragma unroll
    for (int g = 0; g < 2; ++g) {
        const int oc = g * 16 + kgl * 4;
        const float4 bb = *(const float4*)&bias[oc];
        const float bbv[4] = {bb.x, bb.y, bb.z, bb.w};
        float vv[4];
        #pragma unroll
        for (int q = 0; q < 4; ++q) {
            float v = fmaxf(acc[g][0][q], acc[g][1][q]);
            v = fmaxf(v, __shfl_xor(v, 1));
            vv[q] = fmaxf(v + bbv[q], 0.f);
        }
        if (!(col & 1)) {
            unsigned u0 = f2bf(vv[0]) | ((unsigned)f2bf(vv[1]) << 16);
            unsigned u1 = f2bf(vv[2]) | ((unsigned)f2bf(vv[3]) << 16);
            const int pry = Y0 / 2 + wid;
            const int prx = X0 / 2 + (col >> 1);
            uint2 uu; uu.x = u0; uu.y = u1;
            *(uint2*)&out[((size_t)(pry * 256 + prx)) * 32 + oc] = uu;
        }
    }
}

// ================= MFMA conv (convs 2-5) =================
template<int CIN, int COUT, int Hc, int OCB, int CSPLIT>
__global__ __launch_bounds__(256) void conv_mfma(
    const unsigned short* __restrict__ in, const unsigned short* __restrict__ wfrag,
    const float* __restrict__ bias, void* __restrict__ outv)
{
    constexpr int TR = 8;
    constexpr int NOG = OCB / 16;
    constexpr int NG  = COUT / 16;
    constexpr int NCHT = CIN / 32;
    constexpr int NCH = NCHT / CSPLIT;
    constexpr int RPW = TR / 4;
    const int tid = threadIdx.x;
    const int lane = tid & 63, wid = tid >> 6;
    const int col = lane & 15, kgl = lane >> 4;
    const int X0 = blockIdx.x * 16, Y0 = blockIdx.y * TR;
    const int ob = blockIdx.z / CSPLIT, cs = blockIdx.z % CSPLIT;

    __shared__ __align__(16) unsigned short lds[(TR + 2) * 4 * 18 * 8];

    f32x4 acc[NOG][RPW];
    #pragma unroll
    for (int g = 0; g < NOG; ++g) {
        #pragma unroll
        for (int r = 0; r < RPW; ++r) acc[g][r] = {0.f, 0.f, 0.f, 0.f};
    }

    for (int cc = 0; cc < NCH; ++cc) {
        const int ca = cs * NCH + cc;
        __syncthreads();
        constexpr int ITEMS = (TR + 2) * 18 * 4;
        for (int i = tid; i < ITEMS; i += 256) {
            int kg = i & 3, rem = i >> 2;
            int hx = rem % 18, hy = rem / 18;
            int gy = Y0 + hy - 1, gx = X0 + hx - 1;
            short8 v = {0, 0, 0, 0, 0, 0, 0, 0};
            if (gy >= 0 && gy < Hc && gx >= 0 && gx < Hc) {
                v = *(const short8*)&in[((size_t)(gy * Hc + gx)) * CIN + ca * 32 + kg * 8];
            }
            *(short8*)&lds[((hy * 4 + kg) * 18 + hx) * 8] = v;
        }
        __syncthreads();
        #pragma unroll
        for (int t = 0; t < 9; ++t) {
            const int ky = t / 3, kx = t % 3;
            short8 af[NOG];
            #pragma unroll
            for (int g = 0; g < NOG; ++g) {
                af[g] = *(const short8*)&wfrag[((((size_t)t * NG + ob * NOG + g) * NCHT + ca) * 64 + lane) * 8];
            }
            #pragma unroll
            for (int r = 0; r < RPW; ++r) {
                const int py = wid * RPW + r;
                short8 bf = *(const short8*)&lds[(((py + ky) * 4 + kgl) * 18 + col + kx) * 8];
                #pragma unroll
                for (int g = 0; g < NOG; ++g) {
                    acc[g][r] = __builtin_amdgcn_mfma_f32_16x16x32_bf16(af[g], bf, acc[g][r], 0, 0, 0);
                }
            }
        }
    }

    if constexpr (CSPLIT == 1) {
        constexpr int Wp = Hc / 2;
        unsigned short* outp = (unsigned short*)outv;
        #pragma unroll
        for (int g = 0; g < NOG; ++g) {
            const int oc = (ob * NOG + g) * 16 + kgl * 4;
            const float4 bb = *(const float4*)&bias[oc];
            const float bbv[4] = {bb.x, bb.y, bb.z, bb.w};
            #pragma unroll
            for (int pr = 0; pr < RPW / 2; ++pr) {
                float vv[4];
                #pragma unroll
                for (int q = 0; q < 4; ++q) {
                    float v = fmaxf(acc[g][2 * pr][q], acc[g][2 * pr + 1][q]);
                    v = fmaxf(v, __shfl_xor(v, 1));
                    vv[q] = fmaxf(v + bbv[q], 0.f);
                }
                if (!(col & 1)) {
                    unsigned u0 = f2bf(vv[0]) | ((unsigned)f2bf(vv[1]) << 16);
                    unsigned u1 = f2bf(vv[2]) | ((unsigned)f2bf(vv[3]) << 16);
                    const int pry = Y0 / 2 + wid * (RPW / 2) + pr;
                    const int prx = X0 / 2 + (col >> 1);
                    uint2 uu; uu.x = u0; uu.y = u1;
                    *(uint2*)&outp[((size_t)(pry * Wp + prx)) * COUT + oc] = uu;
                }
            }
        }
    } else {
        float* po = (float*)outv;
        #pragma unroll
        for (int g = 0; g < NOG; ++g) {
            #pragma unroll
            for (int r = 0; r < RPW; ++r) {
                const int gy = Y0 + wid * RPW + r;
                #pragma unroll
                for (int q = 0; q < 4; ++q) {
                    const int oc = (ob * NOG + g) * 16 + kgl * 4 + q;
                    po[((size_t)(cs * COUT + oc) * Hc + gy) * Hc + X0 + col] = acc[g][r][q];
                }
            }
        }
    }
}

// sum CS pre-pool f32 partials, add bias, relu, 2x2 maxpool -> f32 channel-major out
template<int COUT, int HP, int CS>
__global__ void finalize_pool(const float* __restrict__ partial, const float* __restrict__ bias,
                              float* __restrict__ out)
{
    int idx = blockIdx.x * 256 + threadIdx.x;
    if (idx >= COUT * HP * HP) return;
    constexpr int H = HP * 2;
    int x = idx & (HP - 1); int rest = idx / HP;
    int y = rest & (HP - 1); int oc = rest / HP;
    float v00 = 0.f, v01 = 0.f, v10 = 0.f, v11 = 0.f;
    #pragma unroll
    for (int cs = 0; cs < CS; ++cs) {
        const float* p = partial + ((size_t)(cs * COUT + oc) * H + 2 * y) * H + 2 * x;
        v00 += p[0]; v01 += p[1]; v10 += p[H]; v11 += p[H + 1];
    }
    float m = fmaxf(fmaxf(v00, v01), fmaxf(v10, v11)) + bias[oc];
    out[idx] = fmaxf(m, 0.f);
}

// ============ fused graph tail ============

__global__ void zero_kernel(float* p) { p[blockIdx.x * 256 + threadIdx.x] = 0.f; }

__global__ void adj_build_kernel(const int* __restrict__ src, const int* __restrict__ dst,
                                 float* adj, float* adjT)
{
    int e = blockIdx.x * 256 + threadIdx.x;
    int s = src[e], d = dst[e];
    atomicAdd(&adj[s * NN + d], 1.0f);   // sums of 1.0 are order-exact
    atomicAdd(&adjT[d * NN + s], 1.0f);
}

// per-node: agg + sage1 + sage2 + softmax + entropy partial. block n, 256 threads.
__global__ __launch_bounds__(256) void node_fused_kernel(
    const float* __restrict__ adjT, const float* __restrict__ org,
    const float* __restrict__ s1wl, const float* __restrict__ s1wr, const float* __restrict__ s1b,
    const float* __restrict__ s2wl, const float* __restrict__ s2wr, const float* __restrict__ s2b,
    float* __restrict__ s_soft, float* __restrict__ s_softT,
    float* __restrict__ x1g, float* __restrict__ entp)
{
    int n = blockIdx.x, t = threadIdx.x;
    __shared__ float rowT[256], orgn[256], aggn[256], red[256], sm[128], red4[4];
    float rT = adjT[n * 256 + t];
    rowT[t] = rT; orgn[t] = org[n * 256 + t];
    __syncthreads();
    float cnt = block_sum_256(rT, red4);
    // agg: 4 independent chains, unrolled -> many loads in flight
    float a0 = 0.f, a1 = 0.f, a2 = 0.f, a3 = 0.f;
    #pragma unroll 8
    for (int s = 0; s < 256; s += 4) {
        a0 = fmaf(rowT[s + 0], org[(s + 0) * 256 + t], a0);
        a1 = fmaf(rowT[s + 1], org[(s + 1) * 256 + t], a1);
        a2 = fmaf(rowT[s + 2], org[(s + 2) * 256 + t], a2);
        a3 = fmaf(rowT[s + 3], org[(s + 3) * 256 + t], a3);
    }
    float acc = (a0 + a1) + (a2 + a3);
    float aggv = (cnt > 0.f) ? acc / cnt : 0.f;
    aggn[t] = aggv;
    float orgv = orgn[t];
    // x1 (2 outputs); block_sum's internal barrier also publishes aggn
    float x10 = block_sum_256(aggv * s1wl[2 * t] + orgv * s1wr[2 * t], red4) + s1b[0];
    float x11 = block_sum_256(aggv * s1wl[2 * t + 1] + orgv * s1wr[2 * t + 1], red4) + s1b[1];
    if (t == 0) { x1g[n * 2 + 0] = x10; x1g[n * 2 + 1] = x11; }
    // s_pre half-split: p = t&127, h = t>>7
    int p = t & 127, h = t >> 7;
    float b0 = 0.f, b1 = 0.f, b2 = 0.f, b3 = 0.f;
    #pragma unroll 8
    for (int k = h * 128; k < h * 128 + 128; k += 2) {
        b0 = fmaf(aggn[k],     s2wl[k * NC + p],       b0);
        b1 = fmaf(orgn[k],     s2wr[k * NC + p],       b1);
        b2 = fmaf(aggn[k + 1], s2wl[(k + 1) * NC + p], b2);
        b3 = fmaf(orgn[k + 1], s2wr[(k + 1) * NC + p], b3);
    }
    red[t] = (b0 + b1) + (b2 + b3);
    __syncthreads();
    if (t < 128) sm[p] = red[t] + red[t + 128] + s2b[p];
    __syncthreads();
    if (t < 128) red[t] = sm[t];
    __syncthreads();
    for (int s = 64; s > 0; s >>= 1) { if (t < s) red[t] = fmaxf(red[t], red[t + s]); __syncthreads(); }
    float mx = red[0];
    __syncthreads();
    float e = 0.f;
    if (t < 128) { e = expf(sm[t] - mx); red[t] = e; } else { red[t] = 0.f; }
    __syncthreads();
    for (int s = 64; s > 0; s >>= 1) { if (t < s) red[t] += red[t + s]; __syncthreads(); }
    float denom = red[0];
    float q = e / denom;
    if (t < 128) {
        s_soft[n * NC + t] = q;
        s_softT[t * 256 + n] = q;
    }
    float ev = (t < 128) ? -q * logf(q + 1e-15f) : 0.f;
    float esum = block_sum_256(ev, red4);
    if (t == 0) entp[n] = esum;
}

// per-row i: link partial + T = adj @ s_soft. block i, 256 threads.
__global__ __launch_bounds__(256) void row_fused_kernel(
    const float* __restrict__ adj, const float* __restrict__ s_soft,
    const float* __restrict__ s_softT, float* __restrict__ T, float* __restrict__ lpart)
{
    int i = blockIdx.x, j = threadIdx.x;
    __shared__ float si[NC], adjrow[256], tbuf[256], red4[4];
    adjrow[j] = adj[i * 256 + j];
    if (j < NC) si[j] = s_soft[i * NC + j];
    __syncthreads();
    float d0 = 0.f, d1 = 0.f, d2 = 0.f, d3 = 0.f;
    #pragma unroll 8
    for (int k = 0; k < NC; k += 4) {
        d0 = fmaf(si[k + 0], s_softT[(k + 0) * 256 + j], d0);
        d1 = fmaf(si[k + 1], s_softT[(k + 1) * 256 + j], d1);
        d2 = fmaf(si[k + 2], s_softT[(k + 2) * 256 + j], d2);
        d3 = fmaf(si[k + 3], s_softT[(k + 3) * 256 + j], d3);
    }
    float dot = (d0 + d1) + (d2 + d3);
    float dd = adjrow[j] - dot;
    float lsum = block_sum_256(dd * dd, red4);
    if (j == 0) lpart[i] = lsum;
    int p = j & 127, h = j >> 7;
    float a0 = 0.f, a1 = 0.f;
    #pragma unroll 8
    for (int k = h * 128; k < h * 128 + 128; k += 2) {
        a0 = fmaf(adjrow[k],     s_soft[k * NC + p],       a0);
        a1 = fmaf(adjrow[k + 1], s_soft[(k + 1) * NC + p], a1);
    }
    tbuf[j] = a0 + a1;
    __syncthreads();
    if (j < 128) T[i * NC + j] = tbuf[j] + tbuf[j + 128];
}

// per-cluster c: adj_pool row + argmax binarize + xpool/tanh. block c, 256 threads.
__global__ __launch_bounds__(256) void cluster_fused_kernel(
    const float* __restrict__ s_softT, const float* __restrict__ T, const float* __restrict__ x1g,
    float* __restrict__ eb_out, float* __restrict__ nodes_out)
{
    int c = blockIdx.x, t = threadIdx.x;
    __shared__ float colc[256], red[256], ap[NC], red4[4];
    colc[t] = s_softT[c * 256 + t];
    __syncthreads();
    int p = t & 127, h = t >> 7;
    float a0 = 0.f, a1 = 0.f;
    #pragma unroll 8
    for (int n = h * 128; n < h * 128 + 128; n += 2) {
        a0 = fmaf(colc[n],     T[n * NC + p],       a0);
        a1 = fmaf(colc[n + 1], T[(n + 1) * NC + p], a1);
    }
    red[t] = a0 + a1;
    __syncthreads();
    if (t < 128) ap[t] = red[t] + red[t + 128];
    __syncthreads();
    if (t < 128) red[t] = ap[t];
    __syncthreads();
    for (int s = 64; s > 0; s >>= 1) { if (t < s) red[t] = fmaxf(red[t], red[t + s]); __syncthreads(); }
    float mx = red[0];
    if (t < 128) eb_out[c * NC + t] = (ap[t] == mx) ? 1.f : 0.f;
    float n0 = tanhf(block_sum_256(colc[t] * x1g[t * 2 + 0], red4));
    float n1 = tanhf(block_sum_256(colc[t] * x1g[t * 2 + 1], red4));
    if (t == 0) { nodes_out[c * 2 + 0] = n0; nodes_out[c * 2 + 1] = n1; }
}

// final: link norm + ent mean + sage3. 1 block, 256 threads.
__global__ __launch_bounds__(256) void final_kernel(
    const float* __restrict__ lpart, const float* __restrict__ entp,
    const float* __restrict__ eb, const float* __restrict__ nodes,
    const float* __restrict__ wl, const float* __restrict__ wr, const float* __restrict__ b,
    float* __restrict__ out_main, float* __restrict__ out_link, float* __restrict__ out_ent)
{
    int t = threadIdx.x;
    __shared__ float red4[4];
    float ls = block_sum_256(lpart[t], red4);
    if (t == 0) out_link[0] = sqrtf(ls) / (float)(NN * NN);
    float es = block_sum_256(entp[t], red4);
    if (t == 0) out_ent[0] = es / (float)NN;
    if (t < NC) {
        int j = t;
        float i0 = 0.f, i1 = 0.f, a00 = 0.f, a01 = 0.f, a10 = 0.f, a11 = 0.f;
        #pragma unroll 8
        for (int i2 = 0; i2 < NC; i2 += 2) {
            float e0 = eb[i2 * NC + j];
            float e1 = eb[(i2 + 1) * NC + j];
            i0 += e0; i1 += e1;
            a00 = fmaf(e0, nodes[i2 * 2 + 0], a00);
            a01 = fmaf(e0, nodes[i2 * 2 + 1], a01);
            a10 = fmaf(e1, nodes[(i2 + 1) * 2 + 0], a10);
            a11 = fmaf(e1, nodes[(i2 + 1) * 2 + 1], a11);
        }
        float indeg = i0 + i1;
        float a0 = a00 + a10, a1 = a01 + a11;
        float inv = (indeg > 0.f) ? 1.f / fmaxf(indeg, 1.f) : 0.f;
        float g0 = a0 * inv, g1 = a1 * inv;
        float n0 = nodes[j * 2 + 0], n1 = nodes[j * 2 + 1];
        out_main[j * 2 + 0] = g0 * wl[0] + g1 * wl[2] + b[0] + n0 * wr[0] + n1 * wr[2];
        out_main[j * 2 + 1] = g0 * wl[1] + g1 * wl[3] + b[1] + n0 * wr[1] + n1 * wr[3];
    }
}

extern "C" void kernel_launch(void* const* d_in, const int* in_sizes, int n_in,
                              void* d_out, int out_size, void* d_ws, size_t ws_size,
                              hipStream_t stream)
{
    const float* input = (const float*)d_in[0];
    const int* eidx = (const int*)d_in[1];
    const int* src = eidx;
    const int* dst = eidx + NE;
    const float* w1 = (const float*)d_in[2];  const float* b1 = (const float*)d_in[3];
    const float* w2 = (const float*)d_in[4];  const float* b2 = (const float*)d_in[5];
    const float* w3 = (const float*)d_in[6];  const float* b3 = (const float*)d_in[7];
    const float* w4 = (const float*)d_in[8];  const float* b4 = (const float*)d_in[9];
    const float* w5 = (const float*)d_in[10]; const float* b5 = (const float*)d_in[11];
    const float* s1_wl = (const float*)d_in[12]; const float* s1_wr = (const float*)d_in[13];
    const float* s1_b  = (const float*)d_in[14];
    const float* s2_wl = (const float*)d_in[15]; const float* s2_wr = (const float*)d_in[16];
    const float* s2_b  = (const float*)d_in[17];
    const float* s3_wl = (const float*)d_in[18]; const float* s3_wr = (const float*)d_in[19];
    const float* s3_b  = (const float*)d_in[20];

    float* ws = (float*)d_ws;
    unsigned short* c1 = (unsigned short*)(ws);
    unsigned short* c2 = (unsigned short*)(ws + 1048576);
    unsigned short* c3 = (unsigned short*)(ws);
    unsigned short* c4 = (unsigned short*)(ws + 1048576);
    float* P5  = ws;
    float* ORG = ws + 1179648;
    unsigned short* f1 = (unsigned short*)(ws + 1572864);
    unsigned short* f2 = (unsigned short*)(ws + 1573888);
    unsigned short* f3 = (unsigned short*)(ws + 1583104);
    unsigned short* f4 = (unsigned short*)(ws + 1619968);
    unsigned short* f5 = (unsigned short*)(ws + 1767424);
    float* adj     = ws + 2062336;
    float* adjT    = ws + 2127872;
    float* s_soft  = ws + 2193408;
    float* T       = ws + 2226176;
    float* x1g     = ws + 2258944;
    float* lpart   = ws + 2259456;
    float* entp    = ws + 2259712;
    float* s_softT = ws + 2259968;   // 128*256

    float* fout = (float*)d_out;
    float* out_main  = fout;
    float* out_link  = fout + 256;
    float* out_ent   = fout + 257;
    float* out_nodes = fout + 258;
    float* out_eb    = fout + 514;

    wfrag_prep_all<<<478, 256, 0, stream>>>(w1, w2, w3, w4, w5, f1, f2, f3, f4, f5);
    zero_kernel<<<512, 256, 0, stream>>>(adj);   // adj + adjT contiguous (131072 floats)
    adj_build_kernel<<<16, 256, 0, stream>>>(src, dst, adj, adjT);

    conv1_mfma<<<dim3(32, 64), 256, 0, stream>>>(input, f1, b1, c1);
    conv_mfma<32,  64, 256, 64, 1><<<dim3(16, 32, 1), 256, 0, stream>>>(c1, f2, b2, c2);
    conv_mfma<64, 128, 128, 64, 1><<<dim3(8, 16, 2),  256, 0, stream>>>(c2, f3, b3, c3);
    conv_mfma<128, 256, 64, 32, 1><<<dim3(4, 8, 8),   256, 0, stream>>>(c3, f4, b4, c4);
    conv_mfma<256, 256, 32, 32, 4><<<dim3(2, 4, 32),  256, 0, stream>>>(c4, f5, b5, P5);
    finalize_pool<256, 16, 4><<<256, 256, 0, stream>>>(P5, b5, ORG);

    node_fused_kernel<<<256, 256, 0, stream>>>(adjT, ORG, s1_wl, s1_wr, s1_b,
                                               s2_wl, s2_wr, s2_b, s_soft, s_softT, x1g, entp);
    row_fused_kernel<<<256, 256, 0, stream>>>(adj, s_soft, s_softT, T, lpart);
    cluster_fused_kernel<<<128, 256, 0, stream>>>(s_softT, T, x1g, out_eb, out_nodes);
    final_kernel<<<1, 256, 0, stream>>>(lpart, entp, out_eb, out_nodes,
                                        s3_wl, s3_wr, s3_b, out_main, out_link, out_ent);
}

// Round 7
// 101.204 us; speedup vs baseline: 7.2987x; 1.1051x over previous
//
#include <hip/hip_runtime.h>
#include <math.h>

#define NN 256
#define NE 4096
#define NC 128

using short8  = __attribute__((ext_vector_type(8))) short;
using short4v = __attribute__((ext_vector_type(4))) short;
using f32x4   = __attribute__((ext_vector_type(4))) float;

static __device__ __forceinline__ unsigned short f2bf(float x) {
    unsigned u = __float_as_uint(x);
    unsigned r = (u + 0x7FFF + ((u >> 16) & 1)) >> 16;   // RNE
    return (unsigned short)r;
}

// wave shfl reduce + cross-wave combine (256 threads). red4 is 4-float LDS scratch.
static __device__ __forceinline__ float block_sum_256(float v, float* red4) {
    #pragma unroll
    for (int o = 32; o > 0; o >>= 1) v += __shfl_xor(v, o);
    __syncthreads();
    if ((threadIdx.x & 63) == 0) red4[threadIdx.x >> 6] = v;
    __syncthreads();
    return (red4[0] + red4[1]) + (red4[2] + red4[3]);
}

// ============ weight prep (convs 1-5) + adj/adjT zeroing, one dispatch ============
__global__ void wfrag_zero_all(const float* __restrict__ w1, const float* __restrict__ w2,
                               const float* __restrict__ w3, const float* __restrict__ w4,
                               const float* __restrict__ w5,
                               unsigned short* __restrict__ f1, unsigned short* __restrict__ f2,
                               unsigned short* __restrict__ f3, unsigned short* __restrict__ f4,
                               unsigned short* __restrict__ f5, float* __restrict__ adjz)
{
    int b = blockIdx.x;
    if (b >= 478) {             // 512 blocks zero adj+adjT (131072 floats contiguous)
        adjz[(b - 478) * 256 + threadIdx.x] = 0.f;
        return;
    }
    if (b == 477) {             // conv1 frags: 2 slots x 2 og x 64 lanes
        int idx = threadIdx.x;
        int lane = idx & 63, rest = idx >> 6;
        int g = rest & 1, slot = rest >> 1;
        int oc = g * 16 + (lane & 15);
        short8 v;
        #pragma unroll
        for (int j = 0; j < 8; ++j) {
            int k = (lane >> 4) * 8 + j;
            float wv = 0.f;
            if (slot == 0) {
                int tap = k >> 2, ch = k & 3;
                if (ch < 3) wv = w1[oc * 27 + ch * 9 + tap];
            } else {
                if (k < 3) wv = w1[oc * 27 + k * 9 + 8];
            }
            v[j] = (short)f2bf(wv);
        }
        *(short8*)&f1[(size_t)idx * 8] = v;
        return;
    }
    const float* w; unsigned short* f; int CIN, NG, NCH, base;
    if (b < 9)        { w = w2; f = f2; CIN = 32;  NG = 4;  NCH = 1; base = 0;   }
    else if (b < 45)  { w = w3; f = f3; CIN = 64;  NG = 8;  NCH = 2; base = 9;   }
    else if (b < 189) { w = w4; f = f4; CIN = 128; NG = 16; NCH = 4; base = 45;  }
    else              { w = w5; f = f5; CIN = 256; NG = 16; NCH = 8; base = 189; }
    int idx = (b - base) * 256 + threadIdx.x;
    int lane = idx & 63, rest = idx >> 6;
    int c = rest % NCH; rest /= NCH;
    int g = rest % NG;  int t = rest / NG;
    if (t >= 9) return;
    int oc = g * 16 + (lane & 15);
    int cin0 = c * 32 + (lane >> 4) * 8;
    short8 v;
    #pragma unroll
    for (int j = 0; j < 8; ++j) {
        v[j] = (short)f2bf(w[((size_t)oc * CIN + cin0 + j) * 9 + t]);
    }
    *(short8*)&f[(size_t)idx * 8] = v;
}

// ============ conv1 MFMA (+ adj build blocks): f32 3x512x512 -> bf16 ch-last [256][256][32]
__global__ __launch_bounds__(256) void conv1_adj_kernel(
    const float* __restrict__ in, const unsigned short* __restrict__ wf1,
    const float* __restrict__ bias, unsigned short* __restrict__ out,
    const int* __restrict__ src, const int* __restrict__ dst,
    float* __restrict__ adj, float* __restrict__ adjT)
{
    const int bid = blockIdx.x;
    const int tid = threadIdx.x;
    if (bid >= 2048) {          // 16 adj-build blocks
        int e = (bid - 2048) * 256 + tid;
        int s = src[e], d = dst[e];
        atomicAdd(&adj[s * NN + d], 1.0f);   // sums of 1.0 are order-exact
        atomicAdd(&adjT[d * NN + s], 1.0f);
        return;
    }
    constexpr int Hc = 512;
    const int lane = tid & 63, wid = tid >> 6;
    const int col = lane & 15, kgl = lane >> 4;
    const int X0 = (bid & 31) * 16, Y0 = (bid >> 5) * 8;
    __shared__ __align__(16) unsigned short lds[10][18][4];
    if (tid < 180) {
        int hy = tid / 18, hx = tid - hy * 18;
        int gy = Y0 + hy - 1, gx = X0 + hx - 1;
        float v0 = 0.f, v1 = 0.f, v2 = 0.f;
        if (gy >= 0 && gy < Hc && gx >= 0 && gx < Hc) {
            v0 = in[0 * 262144 + gy * 512 + gx];
            v1 = in[1 * 262144 + gy * 512 + gx];
            v2 = in[2 * 262144 + gy * 512 + gx];
        }
        uint2 uu;
        uu.x = f2bf(v0) | ((unsigned)f2bf(v1) << 16);
        uu.y = f2bf(v2);
        *(uint2*)&lds[hy][hx][0] = uu;
    }
    short8 af[2][2];
    #pragma unroll
    for (int slot = 0; slot < 2; ++slot) {
        #pragma unroll
        for (int g = 0; g < 2; ++g) {
            af[slot][g] = *(const short8*)&wf1[((size_t)((slot * 2 + g) * 64 + lane)) * 8];
        }
    }
    __syncthreads();
    f32x4 acc[2][2];
    #pragma unroll
    for (int g = 0; g < 2; ++g) {
        #pragma unroll
        for (int r = 0; r < 2; ++r) acc[g][r] = {0.f, 0.f, 0.f, 0.f};
    }
    const int t0 = 2 * kgl, t1 = 2 * kgl + 1;
    const int dy0 = t0 / 3, dx0 = t0 % 3, dy1 = t1 / 3, dx1 = t1 % 3;
    #pragma unroll
    for (int r = 0; r < 2; ++r) {
        const int py = wid * 2 + r;
        short4v lo = *(const short4v*)&lds[py + dy0][col + dx0][0];
        short4v hi = *(const short4v*)&lds[py + dy1][col + dx1][0];
        short8 bf0 = __builtin_shufflevector(lo, hi, 0, 1, 2, 3, 4, 5, 6, 7);
        short4v z4 = {0, 0, 0, 0};
        short4v t8 = z4;
        if (kgl == 0) t8 = *(const short4v*)&lds[py + 2][col + 2][0];
        short8 bf1 = __builtin_shufflevector(t8, z4, 0, 1, 2, 3, 4, 5, 6, 7);
        #pragma unroll
        for (int g = 0; g < 2; ++g) {
            acc[g][r] = __builtin_amdgcn_mfma_f32_16x16x32_bf16(af[0][g], bf0, acc[g][r], 0, 0, 0);
            acc[g][r] = __builtin_amdgcn_mfma_f32_16x16x32_bf16(af[1][g], bf1, acc[g][r], 0, 0, 0);
        }
    }
    #pragma unroll
    for (int g = 0; g < 2; ++g) {
        const int oc = g * 16 + kgl * 4;
        const float4 bb = *(const float4*)&bias[oc];
        const float bbv[4] = {bb.x, bb.y, bb.z, bb.w};
        float vv[4];
        #pragma unroll
        for (int q = 0; q < 4; ++q) {
            float v = fmaxf(acc[g][0][q], acc[g][1][q]);
            v = fmaxf(v, __shfl_xor(v, 1));
            vv[q] = fmaxf(v + bbv[q], 0.f);
        }
        if (!(col & 1)) {
            unsigned u0 = f2bf(vv[0]) | ((unsigned)f2bf(vv[1]) << 16);
            unsigned u1 = f2bf(vv[2]) | ((unsigned)f2bf(vv[3]) << 16);
            const int pry = Y0 / 2 + wid;
            const int prx = X0 / 2 + (col >> 1);
            uint2 uu; uu.x = u0; uu.y = u1;
            *(uint2*)&out[((size_t)(pry * 256 + prx)) * 32 + oc] = uu;
        }
    }
}

// ============ MFMA conv (convs 2-5), async double-buffered staging ============
template<int CIN, int COUT, int Hc, int OCB, int CSPLIT>
__global__ __launch_bounds__(256) void conv_mfma(
    const unsigned short* __restrict__ in, const unsigned short* __restrict__ wfrag,
    const float* __restrict__ bias, void* __restrict__ outv)
{
    constexpr int TR = 8;
    constexpr int NOG = OCB / 16;
    constexpr int NG  = COUT / 16;
    constexpr int NCHT = CIN / 32;
    constexpr int NCH = NCHT / CSPLIT;
    constexpr int RPW = 2;
    constexpr int ITEMS = (TR + 2) * 18 * 4;   // 720
    constexpr int NIT = 3;
    const int tid = threadIdx.x;
    const int lane = tid & 63, wid = tid >> 6;
    const int col = lane & 15, kgl = lane >> 4;
    const int X0 = blockIdx.x * 16, Y0 = blockIdx.y * TR;
    const int ob = blockIdx.z / CSPLIT, cs = blockIdx.z % CSPLIT;

    __shared__ __align__(16) unsigned short lds[2][ITEMS * 8];

    // per-thread staging coords (channel-independent)
    int ioff[NIT]; bool ival[NIT]; int loff[NIT];
    #pragma unroll
    for (int it = 0; it < NIT; ++it) {
        int i = tid + it * 256;
        int kg = i & 3, rem = i >> 2;
        int hx = rem % 18, hy = rem / 18;
        int gy = Y0 + hy - 1, gx = X0 + hx - 1;
        ival[it] = (i < ITEMS) && gy >= 0 && gy < Hc && gx >= 0 && gx < Hc;
        ioff[it] = (gy * Hc + gx) * CIN + kg * 8;
        loff[it] = ((hy * 4 + kg) * 18 + hx) * 8;
    }
    short8 sreg[NIT];
    auto sload = [&](int ca) {
        #pragma unroll
        for (int it = 0; it < NIT; ++it) {
            short8 v = {0, 0, 0, 0, 0, 0, 0, 0};
            if (ival[it]) v = *(const short8*)&in[ioff[it] + ca * 32];
            sreg[it] = v;
        }
    };
    auto swrite = [&](int buf) {
        #pragma unroll
        for (int it = 0; it < NIT; ++it) {
            if (tid + it * 256 < ITEMS) *(short8*)&lds[buf][loff[it]] = sreg[it];
        }
    };

    f32x4 acc[NOG][RPW];
    #pragma unroll
    for (int g = 0; g < NOG; ++g) {
        #pragma unroll
        for (int r = 0; r < RPW; ++r) acc[g][r] = {0.f, 0.f, 0.f, 0.f};
    }

    sload(cs * NCH);
    swrite(0);
    __syncthreads();
    for (int cc = 0; cc < NCH; ++cc) {
        const int ca = cs * NCH + cc;
        if (cc + 1 < NCH) sload(ca + 1);          // issue next chunk's loads early
        const unsigned short* L = &lds[cc & 1][0];
        #pragma unroll
        for (int t = 0; t < 9; ++t) {
            const int ky = t / 3, kx = t % 3;
            short8 af[NOG];
            #pragma unroll
            for (int g = 0; g < NOG; ++g) {
                af[g] = *(const short8*)&wfrag[((((size_t)t * NG + ob * NOG + g) * NCHT + ca) * 64 + lane) * 8];
            }
            #pragma unroll
            for (int r = 0; r < RPW; ++r) {
                const int py = wid * RPW + r;
                short8 bf = *(const short8*)&L[(((py + ky) * 4 + kgl) * 18 + col + kx) * 8];
                #pragma unroll
                for (int g = 0; g < NOG; ++g) {
                    acc[g][r] = __builtin_amdgcn_mfma_f32_16x16x32_bf16(af[g], bf, acc[g][r], 0, 0, 0);
                }
            }
        }
        if (cc + 1 < NCH) { swrite((cc + 1) & 1); __syncthreads(); }
    }

    if constexpr (CSPLIT == 1) {
        constexpr int Wp = Hc / 2;
        unsigned short* outp = (unsigned short*)outv;
        #pragma unroll
        for (int g = 0; g < NOG; ++g) {
            const int oc = (ob * NOG + g) * 16 + kgl * 4;
            const float4 bb = *(const float4*)&bias[oc];
            const float bbv[4] = {bb.x, bb.y, bb.z, bb.w};
            float vv[4];
            #pragma unroll
            for (int q = 0; q < 4; ++q) {
                float v = fmaxf(acc[g][0][q], acc[g][1][q]);
                v = fmaxf(v, __shfl_xor(v, 1));
                vv[q] = fmaxf(v + bbv[q], 0.f);
            }
            if (!(col & 1)) {
                unsigned u0 = f2bf(vv[0]) | ((unsigned)f2bf(vv[1]) << 16);
                unsigned u1 = f2bf(vv[2]) | ((unsigned)f2bf(vv[3]) << 16);
                const int pry = Y0 / 2 + wid;
                const int prx = X0 / 2 + (col >> 1);
                uint2 uu; uu.x = u0; uu.y = u1;
                *(uint2*)&outp[((size_t)(pry * Wp + prx)) * COUT + oc] = uu;
            }
        }
    } else {
        float* po = (float*)outv;
        #pragma unroll
        for (int g = 0; g < NOG; ++g) {
            #pragma unroll
            for (int r = 0; r < RPW; ++r) {
                const int gy = Y0 + wid * RPW + r;
                #pragma unroll
                for (int q = 0; q < 4; ++q) {
                    const int oc = (ob * NOG + g) * 16 + kgl * 4 + q;
                    po[((size_t)(cs * COUT + oc) * Hc + gy) * Hc + X0 + col] = acc[g][r][q];
                }
            }
        }
    }
}

// sum CS pre-pool f32 partials, add bias, relu, 2x2 maxpool -> f32 channel-major out
template<int COUT, int HP, int CS>
__global__ void finalize_pool(const float* __restrict__ partial, const float* __restrict__ bias,
                              float* __restrict__ out)
{
    int idx = blockIdx.x * 256 + threadIdx.x;
    if (idx >= COUT * HP * HP) return;
    constexpr int H = HP * 2;
    int x = idx & (HP - 1); int rest = idx / HP;
    int y = rest & (HP - 1); int oc = rest / HP;
    float v00 = 0.f, v01 = 0.f, v10 = 0.f, v11 = 0.f;
    #pragma unroll
    for (int cs = 0; cs < CS; ++cs) {
        const float* p = partial + ((size_t)(cs * COUT + oc) * H + 2 * y) * H + 2 * x;
        v00 += p[0]; v01 += p[1]; v10 += p[H]; v11 += p[H + 1];
    }
    float m = fmaxf(fmaxf(v00, v01), fmaxf(v10, v11)) + bias[oc];
    out[idx] = fmaxf(m, 0.f);
}

// ============ fused graph tail (unchanged from round 6) ============

__global__ __launch_bounds__(256) void node_fused_kernel(
    const float* __restrict__ adjT, const float* __restrict__ org,
    const float* __restrict__ s1wl, const float* __restrict__ s1wr, const float* __restrict__ s1b,
    const float* __restrict__ s2wl, const float* __restrict__ s2wr, const float* __restrict__ s2b,
    float* __restrict__ s_soft, float* __restrict__ s_softT,
    float* __restrict__ x1g, float* __restrict__ entp)
{
    int n = blockIdx.x, t = threadIdx.x;
    __shared__ float rowT[256], orgn[256], aggn[256], red[256], sm[128], red4[4];
    float rT = adjT[n * 256 + t];
    rowT[t] = rT; orgn[t] = org[n * 256 + t];
    __syncthreads();
    float cnt = block_sum_256(rT, red4);
    float a0 = 0.f, a1 = 0.f, a2 = 0.f, a3 = 0.f;
    #pragma unroll 8
    for (int s = 0; s < 256; s += 4) {
        a0 = fmaf(rowT[s + 0], org[(s + 0) * 256 + t], a0);
        a1 = fmaf(rowT[s + 1], org[(s + 1) * 256 + t], a1);
        a2 = fmaf(rowT[s + 2], org[(s + 2) * 256 + t], a2);
        a3 = fmaf(rowT[s + 3], org[(s + 3) * 256 + t], a3);
    }
    float acc = (a0 + a1) + (a2 + a3);
    float aggv = (cnt > 0.f) ? acc / cnt : 0.f;
    aggn[t] = aggv;
    float orgv = orgn[t];
    float x10 = block_sum_256(aggv * s1wl[2 * t] + orgv * s1wr[2 * t], red4) + s1b[0];
    float x11 = block_sum_256(aggv * s1wl[2 * t + 1] + orgv * s1wr[2 * t + 1], red4) + s1b[1];
    if (t == 0) { x1g[n * 2 + 0] = x10; x1g[n * 2 + 1] = x11; }
    int p = t & 127, h = t >> 7;
    float b0 = 0.f, b1 = 0.f, b2 = 0.f, b3 = 0.f;
    #pragma unroll 8
    for (int k = h * 128; k < h * 128 + 128; k += 2) {
        b0 = fmaf(aggn[k],     s2wl[k * NC + p],       b0);
        b1 = fmaf(orgn[k],     s2wr[k * NC + p],       b1);
        b2 = fmaf(aggn[k + 1], s2wl[(k + 1) * NC + p], b2);
        b3 = fmaf(orgn[k + 1], s2wr[(k + 1) * NC + p], b3);
    }
    red[t] = (b0 + b1) + (b2 + b3);
    __syncthreads();
    if (t < 128) sm[p] = red[t] + red[t + 128] + s2b[p];
    __syncthreads();
    if (t < 128) red[t] = sm[t];
    __syncthreads();
    for (int s = 64; s > 0; s >>= 1) { if (t < s) red[t] = fmaxf(red[t], red[t + s]); __syncthreads(); }
    float mx = red[0];
    __syncthreads();
    float e = 0.f;
    if (t < 128) { e = expf(sm[t] - mx); red[t] = e; } else { red[t] = 0.f; }
    __syncthreads();
    for (int s = 64; s > 0; s >>= 1) { if (t < s) red[t] += red[t + s]; __syncthreads(); }
    float denom = red[0];
    float q = e / denom;
    if (t < 128) {
        s_soft[n * NC + t] = q;
        s_softT[t * 256 + n] = q;
    }
    float ev = (t < 128) ? -q * logf(q + 1e-15f) : 0.f;
    float esum = block_sum_256(ev, red4);
    if (t == 0) entp[n] = esum;
}

__global__ __launch_bounds__(256) void row_fused_kernel(
    const float* __restrict__ adj, const float* __restrict__ s_soft,
    const float* __restrict__ s_softT, float* __restrict__ T, float* __restrict__ lpart)
{
    int i = blockIdx.x, j = threadIdx.x;
    __shared__ float si[NC], adjrow[256], tbuf[256], red4[4];
    adjrow[j] = adj[i * 256 + j];
    if (j < NC) si[j] = s_soft[i * NC + j];
    __syncthreads();
    float d0 = 0.f, d1 = 0.f, d2 = 0.f, d3 = 0.f;
    #pragma unroll 8
    for (int k = 0; k < NC; k += 4) {
        d0 = fmaf(si[k + 0], s_softT[(k + 0) * 256 + j], d0);
        d1 = fmaf(si[k + 1], s_softT[(k + 1) * 256 + j], d1);
        d2 = fmaf(si[k + 2], s_softT[(k + 2) * 256 + j], d2);
        d3 = fmaf(si[k + 3], s_softT[(k + 3) * 256 + j], d3);
    }
    float dot = (d0 + d1) + (d2 + d3);
    float dd = adjrow[j] - dot;
    float lsum = block_sum_256(dd * dd, red4);
    if (j == 0) lpart[i] = lsum;
    int p = j & 127, h = j >> 7;
    float a0 = 0.f, a1 = 0.f;
    #pragma unroll 8
    for (int k = h * 128; k < h * 128 + 128; k += 2) {
        a0 = fmaf(adjrow[k],     s_soft[k * NC + p],       a0);
        a1 = fmaf(adjrow[k + 1], s_soft[(k + 1) * NC + p], a1);
    }
    tbuf[j] = a0 + a1;
    __syncthreads();
    if (j < 128) T[i * NC + j] = tbuf[j] + tbuf[j + 128];
}

__global__ __launch_bounds__(256) void cluster_fused_kernel(
    const float* __restrict__ s_softT, const float* __restrict__ T, const float* __restrict__ x1g,
    float* __restrict__ eb_out, float* __restrict__ nodes_out)
{
    int c = blockIdx.x, t = threadIdx.x;
    __shared__ float colc[256], red[256], ap[NC], red4[4];
    colc[t] = s_softT[c * 256 + t];
    __syncthreads();
    int p = t & 127, h = t >> 7;
    float a0 = 0.f, a1 = 0.f;
    #pragma unroll 8
    for (int n = h * 128; n < h * 128 + 128; n += 2) {
        a0 = fmaf(colc[n],     T[n * NC + p],       a0);
        a1 = fmaf(colc[n + 1], T[(n + 1) * NC + p], a1);
    }
    red[t] = a0 + a1;
    __syncthreads();
    if (t < 128) ap[t] = red[t] + red[t + 128];
    __syncthreads();
    if (t < 128) red[t] = ap[t];
    __syncthreads();
    for (int s = 64; s > 0; s >>= 1) { if (t < s) red[t] = fmaxf(red[t], red[t + s]); __syncthreads(); }
    float mx = red[0];
    if (t < 128) eb_out[c * NC + t] = (ap[t] == mx) ? 1.f : 0.f;
    float n0 = tanhf(block_sum_256(colc[t] * x1g[t * 2 + 0], red4));
    float n1 = tanhf(block_sum_256(colc[t] * x1g[t * 2 + 1], red4));
    if (t == 0) { nodes_out[c * 2 + 0] = n0; nodes_out[c * 2 + 1] = n1; }
}

__global__ __launch_bounds__(256) void final_kernel(
    const float* __restrict__ lpart, const float* __restrict__ entp,
    const float* __restrict__ eb, const float* __restrict__ nodes,
    const float* __restrict__ wl, const float* __restrict__ wr, const float* __restrict__ b,
    float* __restrict__ out_main, float* __restrict__ out_link, float* __restrict__ out_ent)
{
    int t = threadIdx.x;
    __shared__ float red4[4];
    float ls = block_sum_256(lpart[t], red4);
    if (t == 0) out_link[0] = sqrtf(ls) / (float)(NN * NN);
    float es = block_sum_256(entp[t], red4);
    if (t == 0) out_ent[0] = es / (float)NN;
    if (t < NC) {
        int j = t;
        float i0 = 0.f, i1 = 0.f, a00 = 0.f, a01 = 0.f, a10 = 0.f, a11 = 0.f;
        #pragma unroll 8
        for (int i2 = 0; i2 < NC; i2 += 2) {
            float e0 = eb[i2 * NC + j];
            float e1 = eb[(i2 + 1) * NC + j];
            i0 += e0; i1 += e1;
            a00 = fmaf(e0, nodes[i2 * 2 + 0], a00);
            a01 = fmaf(e0, nodes[i2 * 2 + 1], a01);
            a10 = fmaf(e1, nodes[(i2 + 1) * 2 + 0], a10);
            a11 = fmaf(e1, nodes[(i2 + 1) * 2 + 1], a11);
        }
        float indeg = i0 + i1;
        float a0 = a00 + a10, a1 = a01 + a11;
        float inv = (indeg > 0.f) ? 1.f / fmaxf(indeg, 1.f) : 0.f;
        float g0 = a0 * inv, g1 = a1 * inv;
        float n0 = nodes[j * 2 + 0], n1 = nodes[j * 2 + 1];
        out_main[j * 2 + 0] = g0 * wl[0] + g1 * wl[2] + b[0] + n0 * wr[0] + n1 * wr[2];
        out_main[j * 2 + 1] = g0 * wl[1] + g1 * wl[3] + b[1] + n0 * wr[1] + n1 * wr[3];
    }
}

extern "C" void kernel_launch(void* const* d_in, const int* in_sizes, int n_in,
                              void* d_out, int out_size, void* d_ws, size_t ws_size,
                              hipStream_t stream)
{
    const float* input = (const float*)d_in[0];
    const int* eidx = (const int*)d_in[1];
    const int* src = eidx;
    const int* dst = eidx + NE;
    const float* w1 = (const float*)d_in[2];  const float* b1 = (const float*)d_in[3];
    const float* w2 = (const float*)d_in[4];  const float* b2 = (const float*)d_in[5];
    const float* w3 = (const float*)d_in[6];  const float* b3 = (const float*)d_in[7];
    const float* w4 = (const float*)d_in[8];  const float* b4 = (const float*)d_in[9];
    const float* w5 = (const float*)d_in[10]; const float* b5 = (const float*)d_in[11];
    const float* s1_wl = (const float*)d_in[12]; const float* s1_wr = (const float*)d_in[13];
    const float* s1_b  = (const float*)d_in[14];
    const float* s2_wl = (const float*)d_in[15]; const float* s2_wr = (const float*)d_in[16];
    const float* s2_b  = (const float*)d_in[17];
    const float* s3_wl = (const float*)d_in[18]; const float* s3_wr = (const float*)d_in[19];
    const float* s3_b  = (const float*)d_in[20];

    float* ws = (float*)d_ws;
    unsigned short* c1 = (unsigned short*)(ws);
    unsigned short* c2 = (unsigned short*)(ws + 1048576);
    unsigned short* c3 = (unsigned short*)(ws);
    unsigned short* c4 = (unsigned short*)(ws + 1048576);
    float* P5  = ws;
    float* ORG = ws + 1179648;
    unsigned short* f1 = (unsigned short*)(ws + 1572864);
    unsigned short* f2 = (unsigned short*)(ws + 1573888);
    unsigned short* f3 = (unsigned short*)(ws + 1583104);
    unsigned short* f4 = (unsigned short*)(ws + 1619968);
    unsigned short* f5 = (unsigned short*)(ws + 1767424);
    float* adj     = ws + 2062336;
    float* adjT    = ws + 2127872;
    float* s_soft  = ws + 2193408;
    float* T       = ws + 2226176;
    float* x1g     = ws + 2258944;
    float* lpart   = ws + 2259456;
    float* entp    = ws + 2259712;
    float* s_softT = ws + 2259968;   // 128*256

    float* fout = (float*)d_out;
    float* out_main  = fout;
    float* out_link  = fout + 256;
    float* out_ent   = fout + 257;
    float* out_nodes = fout + 258;
    float* out_eb    = fout + 514;

    wfrag_zero_all<<<990, 256, 0, stream>>>(w1, w2, w3, w4, w5, f1, f2, f3, f4, f5, adj);
    conv1_adj_kernel<<<2064, 256, 0, stream>>>(input, f1, b1, c1, src, dst, adj, adjT);
    conv_mfma<32,  64, 256, 64, 1><<<dim3(16, 32, 1), 256, 0, stream>>>(c1, f2, b2, c2);
    conv_mfma<64, 128, 128, 64, 1><<<dim3(8, 16, 2),  256, 0, stream>>>(c2, f3, b3, c3);
    conv_mfma<128, 256, 64, 32, 1><<<dim3(4, 8, 8),   256, 0, stream>>>(c3, f4, b4, c4);
    conv_mfma<256, 256, 32, 32, 4><<<dim3(2, 4, 32),  256, 0, stream>>>(c4, f5, b5, P5);
    finalize_pool<256, 16, 4><<<256, 256, 0, stream>>>(P5, b5, ORG);

    node_fused_kernel<<<256, 256, 0, stream>>>(adjT, ORG, s1_wl, s1_wr, s1_b,
                                               s2_wl, s2_wr, s2_b, s_soft, s_softT, x1g, entp);
    row_fused_kernel<<<256, 256, 0, stream>>>(adj, s_soft, s_softT, T, lpart);
    cluster_fused_kernel<<<128, 256, 0, stream>>>(s_softT, T, x1g, out_eb, out_nodes);
    final_kernel<<<1, 256, 0, stream>>>(lpart, entp, out_eb, out_nodes,
                                        s3_wl, s3_wr, s3_b, out_main, out_link, out_ent);
}